// Round 1
// baseline (2598.879 us; speedup 1.0000x reference)
//
#include <hip/hip_runtime.h>
#include <math.h>

#define NATOMS 50000
#define NEDGES 400000
#define NG 10
#define JRBF 500          // 10 gates * 50 rbf
#define JSV  60           // 10 gates * 6 scalar feats
#define JTOT 580          // 500 + 60 + 10 (Q) + 10 (U)
#define TE   16           // edges per block in k_edge

// ---- d_out layout (float elements) ----
#define OUT_VEC   6400000LL
#define OUT_Z     25600000LL
#define OUT_POS   25650000LL
#define OUT_BATCH 25800000LL

// ---- workspace layout (float elements) ----
#define WS_M1  0LL
#define WS_M0  65536LL
#define WS_C0  (WS_M0 + 12800)
#define WS_M2  (WS_C0 + 256)
#define WS_CC  (WS_M2 + 1536)
#define WS_AI  (WS_CC + 256)
#define WS_AJ  (WS_AI + 25600)
#define WS_GI  (WS_AJ + 25600)
#define WS_GJ  (WS_GI + 25600)
#define WS_HI  (WS_GJ + 25600)
#define WS_HJ  (WS_HI + 128000)
#define WS_PT  (WS_HJ + 128000)
#define WS_SMALL_END (WS_PT + 74240)     // 513,024 floats (~2.05 MB)
#define WS_EO  WS_SMALL_END              // edge_out [400000][128]
#define WS_EV  (WS_EO + 51200000LL)      // ev [400000][3]
#define WS_INT (WS_EV + 1200000LL)       // int region: cnt/start/cursor/csr
#define WS_END (WS_INT + 550000LL)       // ~213.9 MB total

// ---------------- precompute kernels (all tiny) ----------------

// out[r][c] = sum_k A[r*lda+k] * B[k*256+c] (+ bias[c]); N=256 cols
__global__ void k_mm256(const float* __restrict__ A, int lda,
                        const float* __restrict__ B,
                        const float* __restrict__ bias,
                        float* __restrict__ out, int K)
{
    const int r = blockIdx.x, c = threadIdx.x;
    const float* a = A + (long long)r * lda;
    float acc = bias ? bias[c] : 0.0f;
    for (int k = 0; k < K; ++k) acc += a[k] * B[k * 256 + c];
    out[(long long)r * 256 + c] = acc;
}

// H[z*10+g][f] = sum_c G[z][c] * W_exp[g][c][f]
__global__ void k_htable(const float* __restrict__ G,
                         const float* __restrict__ Wexp,
                         float* __restrict__ H)
{
    const int zg = blockIdx.x;             // 0..999
    const int zz = zg / 10, g = zg - zz * 10;
    const int f = threadIdx.x;
    const float* grow = G + (long long)zz * 256;
    const float* wp = Wexp + (long long)g * 256 * 128 + f;
    float acc = 0.0f;
    for (int c = 0; c < 256; ++c) acc += grow[c] * wp[c * 128];
    H[(long long)zg * 128 + f] = acc;
}

// PT[j][f], j in [0,580)
__global__ void k_pt(const float* __restrict__ M0, const float* __restrict__ M2,
                     const float* __restrict__ c0, const float* __restrict__ cc,
                     const float* __restrict__ Wexp, const float* __restrict__ b_exp,
                     float* __restrict__ PT)
{
    const int j = blockIdx.x, f = threadIdx.x;
    const float* arow;
    int g;
    float bias = 0.0f;
    if (j < JRBF)                { g = j / 50; arow = M0 + (long long)(j - g * 50) * 256; }
    else if (j < JRBF + JSV)     { const int jj = j - JRBF; g = jj / 6; arow = M2 + (long long)(jj - g * 6) * 256; }
    else if (j < JRBF + JSV + NG){ g = j - (JRBF + JSV); arow = c0; }
    else                         { g = j - (JRBF + JSV + NG); arow = cc; bias = b_exp[g * 128 + f]; }
    const float* wp = Wexp + (long long)g * 256 * 128 + f;
    float acc = bias;
    for (int c = 0; c < 256; ++c) acc += arow[c] * wp[c * 128];
    PT[(long long)j * 128 + f] = acc;
}

// ---------------- edge kernel ----------------
// block = 256 threads, TE=16 edges. Coefficient build in LDS, then
// [16 x 580] @ [580 x 128] contraction + gate-blended H gathers.
__global__ void __launch_bounds__(256) k_edge(
    const float* __restrict__ edge_vec,
    const int* __restrict__ esrc, const int* __restrict__ edst,
    const int* __restrict__ zarr, const float* __restrict__ tpar,
    const float* __restrict__ Hi, const float* __restrict__ Hj,
    const float* __restrict__ PT,
    float* __restrict__ out,            // atomic mode target (d_out), else unused
    float* __restrict__ eo,             // csr mode: edge_out staging
    float* __restrict__ evb,            // csr mode: normalized edge vecs
    const int csr_mode)
{
    __shared__ __align__(16) float w[JTOT][TE];
    __shared__ float sgate[NG][TE];
    __shared__ float ssv[6][TE];
    __shared__ float sev[3][TE];
    __shared__ int   szi[TE], szj[TE], ssrc[TE];

    const int tid   = threadIdx.x;
    const int eloc  = tid & (TE - 1);
    const int slice = tid >> 4;                         // 0..15
    const long long ebase = (long long)blockIdx.x * TE;
    const int e = (int)ebase + eloc;                    // grid sized exactly

    // per-edge scalars (each of 16 slices for its edge)
    const float vx = edge_vec[e * 3 + 0];
    const float vy = edge_vec[e * 3 + 1];
    const float vz = edge_vec[e * 3 + 2];
    const float d2 = vx * vx + vy * vy + vz * vz;
    const float d  = sqrtf(d2);
    const float C  = (d < 5.0f) ? 0.5f * (cosf(d * 0.6283185307179586f) + 1.0f) : 0.0f;

    if (slice == 0) {
        float g0[NG];
        float m = -3.0e38f;
#pragma unroll
        for (int g = 0; g < NG; ++g) {
            float rg = 1.0f / fmaxf(fabsf(d - tpar[g]), 1e-8f);
            g0[g] = rg; m = fmaxf(m, rg);
        }
        float ssum = 0.0f;
#pragma unroll
        for (int g = 0; g < NG; ++g) { float ex = expf(g0[g] - m); g0[g] = ex; ssum += ex; }
        const float inv = 1.0f / ssum;
#pragma unroll
        for (int g = 0; g < NG; ++g) sgate[g][eloc] = g0[g] * inv;
        ssv[0][eloc] = d2;        ssv[1][eloc] = d2 * d;  ssv[2][eloc] = d2 * d2;
        ssv[3][eloc] = sqrtf(d);  ssv[4][eloc] = logf(d); ssv[5][eloc] = d;
        const float invd = 1.0f / d;
        sev[0][eloc] = vx * invd; sev[1][eloc] = vy * invd; sev[2][eloc] = vz * invd;
        const int si = esrc[e], dj = edst[e];
        ssrc[eloc] = si; szi[eloc] = zarr[si]; szj[eloc] = zarr[dj];
    }
    __syncthreads();

    // fill coefficient rows w[j][eloc]
    {
        const float DELTA = 5.0f / 49.0f;
        const float COEFF = -0.5f / (DELTA * DELTA);
        const int jbeg = slice * 37;
        const int jend = min(jbeg + 37, JTOT);
        for (int j = jbeg; j < jend; ++j) {
            float val;
            if (j < JRBF) {
                const int g = j / 50, k = j - (j / 50) * 50;
                const float t = d - (float)k * DELTA;
                val = C * sgate[g][eloc] * expf(COEFF * t * t);
            } else if (j < JRBF + JSV) {
                const int jj = j - JRBF;
                const int g = jj / 6, m2 = jj - (jj / 6) * 6;
                val = sgate[g][eloc] * ssv[m2][eloc];
            } else if (j < JRBF + JSV + NG) {
                val = C * sgate[j - (JRBF + JSV)][eloc];
            } else {
                val = sgate[j - (JRBF + JSV + NG)][eloc];
            }
            w[j][eloc] = val;
        }
    }
    __syncthreads();

    // contraction: thread owns 2 edges x 4 features
    const int fgrp = tid & 31;
    const int f0 = fgrp * 4;
    const int e0 = (tid >> 5) * 2;

    float4 acc[2];
    acc[0] = make_float4(0.f, 0.f, 0.f, 0.f);
    acc[1] = make_float4(0.f, 0.f, 0.f, 0.f);

    const float4* __restrict__ PT4 = (const float4*)PT;
    for (int j = 0; j < JTOT; ++j) {
        const float4 p = PT4[j * 32 + fgrp];
        const float2 wv = *(const float2*)&w[j][e0];
        acc[0].x += wv.x * p.x; acc[0].y += wv.x * p.y;
        acc[0].z += wv.x * p.z; acc[0].w += wv.x * p.w;
        acc[1].x += wv.y * p.x; acc[1].y += wv.y * p.y;
        acc[1].z += wv.y * p.z; acc[1].w += wv.y * p.w;
    }

    // gate-blended z-tables
#pragma unroll
    for (int ei = 0; ei < 2; ++ei) {
        const int el = e0 + ei;
        const int zi = szi[el], zj = szj[el];
        const float4* __restrict__ HiP = (const float4*)(Hi + (long long)zi * 1280);
        const float4* __restrict__ HjP = (const float4*)(Hj + (long long)zj * 1280);
#pragma unroll
        for (int g = 0; g < NG; ++g) {
            const float ge = sgate[g][el];
            const float4 hi = HiP[g * 32 + fgrp];
            const float4 hj = HjP[g * 32 + fgrp];
            acc[ei].x += ge * (hi.x + hj.x);
            acc[ei].y += ge * (hi.y + hj.y);
            acc[ei].z += ge * (hi.z + hj.z);
            acc[ei].w += ge * (hi.w + hj.w);
        }
    }

    if (csr_mode) {
#pragma unroll
        for (int ei = 0; ei < 2; ++ei) {
            const long long eg = ebase + (e0 + ei);
            *(float4*)(eo + eg * 128 + f0) = acc[ei];
        }
        if (tid < TE) {
            const long long eg = ebase + tid;
            evb[eg * 3 + 0] = sev[0][tid];
            evb[eg * 3 + 1] = sev[1][tid];
            evb[eg * 3 + 2] = sev[2][tid];
        }
    } else {
#pragma unroll
        for (int ei = 0; ei < 2; ++ei) {
            const int el = e0 + ei;
            const int src = ssrc[el];
            const float evx = sev[0][el], evy = sev[1][el], evz = sev[2][el];
            float* ao = out + (long long)src * 128 + f0;
            float* vp = out + OUT_VEC + (long long)src * 384 + f0;
            const float y[4] = {acc[ei].x, acc[ei].y, acc[ei].z, acc[ei].w};
#pragma unroll
            for (int fi = 0; fi < 4; ++fi) {
                atomicAdd(ao + fi, y[fi]);
                atomicAdd(vp + fi,       evx * y[fi]);
                atomicAdd(vp + 128 + fi, evy * y[fi]);
                atomicAdd(vp + 256 + fi, evz * y[fi]);
            }
        }
    }
}

// ---------------- CSR build + gather ----------------

__global__ void k_hist(const int* __restrict__ esrc, int* __restrict__ cnt)
{
    const int e = blockIdx.x * 256 + threadIdx.x;
    if (e < NEDGES) atomicAdd(&cnt[esrc[e]], 1);
}

__global__ void k_scan(const int* __restrict__ cnt, int* __restrict__ startp,
                       int* __restrict__ cursor, int n)
{
    __shared__ int part[1024];
    const int tid = threadIdx.x;
    const int chunk = (n + 1023) >> 10;
    const int lo = tid * chunk;
    const int hi = min(lo + chunk, n);
    int s = 0;
    for (int i = lo; i < hi; ++i) s += cnt[i];
    part[tid] = s;
    __syncthreads();
    for (int off = 1; off < 1024; off <<= 1) {
        int t = part[tid];
        if (tid >= off) t += part[tid - off];
        __syncthreads();
        part[tid] = t;
        __syncthreads();
    }
    int run = (tid == 0) ? 0 : part[tid - 1];
    for (int i = lo; i < hi; ++i) { startp[i] = run; cursor[i] = run; run += cnt[i]; }
}

__global__ void k_fill(const int* __restrict__ esrc, int* __restrict__ cursor,
                       int* __restrict__ csr)
{
    const int e = blockIdx.x * 256 + threadIdx.x;
    if (e < NEDGES) {
        const int pos = atomicAdd(&cursor[esrc[e]], 1);
        csr[pos] = e;
    }
}

// one wave per atom, 4 atoms per block
__global__ void __launch_bounds__(256) k_gather(
    const float* __restrict__ eo, const float* __restrict__ evb,
    const int* __restrict__ startp, const int* __restrict__ cnt,
    const int* __restrict__ csr, float* __restrict__ out)
{
    const int atom = blockIdx.x * 4 + (threadIdx.x >> 6);
    const int lane = threadIdx.x & 63;
    if (atom >= NATOMS) return;
    const int s = startp[atom], len = cnt[atom];
    float a0 = 0, a1 = 0, v00 = 0, v01 = 0, v10 = 0, v11 = 0, v20 = 0, v21 = 0;
    for (int i = 0; i < len; ++i) {
        const int eid = csr[s + i];
        const float evx = evb[eid * 3], evy = evb[eid * 3 + 1], evz = evb[eid * 3 + 2];
        const float y0 = eo[(long long)eid * 128 + lane];
        const float y1 = eo[(long long)eid * 128 + 64 + lane];
        a0 += y0; a1 += y1;
        v00 += evx * y0; v01 += evx * y1;
        v10 += evy * y0; v11 += evy * y1;
        v20 += evz * y0; v21 += evz * y1;
    }
    float* ao = out + (long long)atom * 128;
    ao[lane] = a0; ao[64 + lane] = a1;
    float* vp = out + OUT_VEC + (long long)atom * 384;
    vp[lane] = v00;       vp[64 + lane] = v01;
    vp[128 + lane] = v10; vp[192 + lane] = v11;
    vp[256 + lane] = v20; vp[320 + lane] = v21;
}

__global__ void k_tail(const int* __restrict__ z, const float* __restrict__ pos,
                       const int* __restrict__ batch, float* __restrict__ out)
{
    const int i = blockIdx.x * 256 + threadIdx.x;
    if (i < NATOMS) {
        out[OUT_Z + i] = (float)z[i];
        out[OUT_BATCH + i] = (float)batch[i];
    }
    if (i < 3 * NATOMS) out[OUT_POS + i] = pos[i];
}

// ---------------- launch ----------------

extern "C" void kernel_launch(void* const* d_in, const int* in_sizes, int n_in,
                              void* d_out, int out_size, void* d_ws, size_t ws_size,
                              hipStream_t stream)
{
    const int*   z        = (const int*)d_in[0];
    const float* pos      = (const float*)d_in[1];
    const int*   batch    = (const int*)d_in[2];
    const int*   esrc     = (const int*)d_in[3];
    const int*   edst     = esrc + NEDGES;
    const float* edge_vec = (const float*)d_in[4];
    const float* emb      = (const float*)d_in[5];
    const float* W_dist   = (const float*)d_in[6];
    const float* b_dist   = (const float*)d_in[7];
    const float* W_dt     = (const float*)d_in[8];
    const float* b_dt     = (const float*)d_in[9];
    const float* W_ai     = (const float*)d_in[10];
    const float* b_ai     = (const float*)d_in[11];
    const float* W_aj     = (const float*)d_in[12];
    const float* b_aj     = (const float*)d_in[13];
    const float* W_gamma  = (const float*)d_in[14];
    const float* b_gamma  = (const float*)d_in[15];
    const float* W_exp    = (const float*)d_in[16];
    const float* b_exp    = (const float*)d_in[17];
    const float* tpar     = (const float*)d_in[18];

    float* out = (float*)d_out;
    float* W   = (float*)d_ws;

    const float* Wg1 = W_gamma;
    const float* Wg2 = W_gamma + 256 * 256;
    const float* Wg3 = W_gamma + 512 * 256;

    float* M1 = W + WS_M1;
    float* M0 = W + WS_M0;
    float* c0 = W + WS_C0;
    float* M2 = W + WS_M2;
    float* cc = W + WS_CC;
    float* Ai = W + WS_AI;
    float* Aj = W + WS_AJ;
    float* Gi = W + WS_GI;
    float* Gj = W + WS_GJ;
    float* Hi = W + WS_HI;
    float* Hj = W + WS_HJ;
    float* PT = W + WS_PT;

    // precompute chain (stream-serialized)
    k_mm256<<<256, 256, 0, stream>>>(W_dt, 256, Wg3, nullptr, M1, 256);          // M1 = W_dt[:256]@Wg3
    k_mm256<<<50,  256, 0, stream>>>(W_dist, 256, M1, nullptr, M0, 256);         // M0 = W_dist@M1
    k_mm256<<<1,   256, 0, stream>>>(b_dist, 0, M1, nullptr, c0, 256);           // c0 = b_dist@M1
    k_mm256<<<6,   256, 0, stream>>>(W_dt + 256 * 256, 256, Wg3, nullptr, M2, 256); // M2 = W_dt[256:262]@Wg3
    k_mm256<<<1,   256, 0, stream>>>(b_dt, 0, Wg3, b_gamma, cc, 256);            // cc = b_dt@Wg3 + b_gamma
    k_mm256<<<100, 256, 0, stream>>>(emb, 256, W_ai, b_ai, Ai, 256);
    k_mm256<<<100, 256, 0, stream>>>(emb, 256, W_aj, b_aj, Aj, 256);
    k_mm256<<<100, 256, 0, stream>>>(Ai, 256, Wg1, nullptr, Gi, 256);
    k_mm256<<<100, 256, 0, stream>>>(Aj, 256, Wg2, nullptr, Gj, 256);
    k_htable<<<1000, 128, 0, stream>>>(Gi, W_exp, Hi);
    k_htable<<<1000, 128, 0, stream>>>(Gj, W_exp, Hj);
    k_pt<<<JTOT, 128, 0, stream>>>(M0, M2, c0, cc, W_exp, b_exp, PT);

    const size_t need_csr = (size_t)WS_END * sizeof(float);
    const bool use_csr = (ws_size >= need_csr);

    if (use_csr) {
        float* eo  = W + WS_EO;
        float* evb = W + WS_EV;
        int* cnt    = (int*)(W + WS_INT);
        int* startp = cnt + NATOMS;
        int* cursor = startp + NATOMS;
        int* csr    = cursor + NATOMS;

        hipMemsetAsync(cnt, 0, NATOMS * sizeof(int), stream);
        k_edge<<<NEDGES / TE, 256, 0, stream>>>(edge_vec, esrc, edst, z, tpar,
                                                Hi, Hj, PT, nullptr, eo, evb, 1);
        k_hist<<<(NEDGES + 255) / 256, 256, 0, stream>>>(esrc, cnt);
        k_scan<<<1, 1024, 0, stream>>>(cnt, startp, cursor, NATOMS);
        k_fill<<<(NEDGES + 255) / 256, 256, 0, stream>>>(esrc, cursor, csr);
        k_gather<<<(NATOMS + 3) / 4, 256, 0, stream>>>(eo, evb, startp, cnt, csr, out);
    } else {
        hipMemsetAsync(out, 0, (size_t)OUT_Z * sizeof(float), stream);
        k_edge<<<NEDGES / TE, 256, 0, stream>>>(edge_vec, esrc, edst, z, tpar,
                                                Hi, Hj, PT, out, nullptr, nullptr, 0);
    }

    k_tail<<<(3 * NATOMS + 255) / 256, 256, 0, stream>>>(z, pos, batch, out);
}

// Round 2
// 2070.826 us; speedup vs baseline: 1.2550x; 1.2550x over previous
//
#include <hip/hip_runtime.h>
#include <math.h>

typedef __bf16 bf16;
typedef __bf16 bf16x8 __attribute__((ext_vector_type(8)));
typedef float  f32x16 __attribute__((ext_vector_type(16)));

#define NATOMS 50000
#define NEDGES 400000
#define NG 10
#define NZ 100
#define BE 64                  // edges per k_edge block
#define NBLK 6350              // >= ceil((400000 + 100*63)/64)
#define NCHUNK_PT 37           // PT K-chunks of 16 (covers K=0..591, real 0..579)
#define KSTEPS 38              // 37 PT chunks + 1 Hj chunk
#define APAD 616               // A row stride (bf16) -> 308 dw = 20 mod 32, conflict-free

// ---- d_out layout (float elements) ----
#define OUT_VEC   6400000LL
#define OUT_Z     25600000LL
#define OUT_POS   25650000LL
#define OUT_BATCH 25800000LL

// ---- workspace layout (float units) ----
static const long long WS_M1  = 0;                   // 256*256
static const long long WS_M0  = WS_M1 + 65536;       // 50*256
static const long long WS_C0  = WS_M0 + 12800;       // 256
static const long long WS_M2  = WS_C0 + 256;         // 6*256
static const long long WS_CC  = WS_M2 + 1536;        // 256
static const long long WS_AI  = WS_CC + 256;         // 100*256
static const long long WS_AJ  = WS_AI + 25600;
static const long long WS_GI  = WS_AJ + 25600;
static const long long WS_GJ  = WS_GI + 25600;
static const long long WS_HI  = WS_GJ + 25600;       // 100*10*128 f32
static const long long WS_HJ  = WS_HI + 128000;      // 100*10*128 f32
static const long long WS_PTC = WS_HJ + 128000;      // 37*128*24 bf16 = 56832 float units
static const long long WS_GT  = WS_PTC + 56832;      // gates [NEDGES][12] f32
static const long long WS_EV  = WS_GT + 4800000;     // evb [NEDGES][3] f32
static const long long WS_EO  = WS_EV + 1200000;     // eo bf16 [NEDGES][128] = 25.6M float units
static const long long WS_I   = WS_EO + 25600000;    // int region below
// int region offsets (ints)
#define I_CNT   0
#define I_START 50000
#define I_CUR   100000
#define I_CSR   150000
#define I_ZB    550000
#define I_ZC    550128
#define I_PERM  550384              // NBLK*64 = 406400 ints
#define I_B2Z   (550384 + 406400)   // NBLK ints

// ---------------- precompute kernels ----------------

__global__ void k_mm256(const float* __restrict__ A, int lda,
                        const float* __restrict__ B,
                        const float* __restrict__ bias,
                        float* __restrict__ out, int K)
{
    const int r = blockIdx.x, c = threadIdx.x;
    const float* a = A + (long long)r * lda;
    float acc = bias ? bias[c] : 0.0f;
    for (int k = 0; k < K; ++k) acc += a[k] * B[k * 256 + c];
    out[(long long)r * 256 + c] = acc;
}

__global__ void k_htable(const float* __restrict__ G,
                         const float* __restrict__ Wexp,
                         float* __restrict__ H)
{
    const int zg = blockIdx.x;             // 0..999
    const int zz = zg / 10, g = zg - zz * 10;
    const int f = threadIdx.x;
    const float* grow = G + (long long)zz * 256;
    const float* wp = Wexp + (long long)g * 256 * 128 + f;
    float acc = 0.0f;
    for (int c = 0; c < 256; ++c) acc += grow[c] * wp[c * 128];
    H[(long long)zg * 128 + f] = acc;
}

// PTc[ck][f][kl] bf16, ck in [0,37), kl in [0,24) (16 real K + 8 zero pad)
__global__ void k_ptc(const float* __restrict__ M0, const float* __restrict__ M2,
                      const float* __restrict__ c0, const float* __restrict__ cc,
                      const float* __restrict__ Wexp, const float* __restrict__ b_exp,
                      bf16* __restrict__ PTc)
{
    const int ck = blockIdx.x;
    const int f  = threadIdx.x;           // 0..127
    for (int kl = 0; kl < 24; ++kl) {
        float val = 0.0f;
        const int j = ck * 16 + kl;
        if (kl < 16 && j < 580) {
            const float* arow; int g; float bias = 0.0f;
            if (j < 500)      { g = j / 50; arow = M0 + (long long)(j - g * 50) * 256; }
            else if (j < 560) { const int jj = j - 500; g = jj / 6; arow = M2 + (long long)(jj - g * 6) * 256; }
            else if (j < 570) { g = j - 560; arow = c0; }
            else              { g = j - 570; arow = cc; bias = b_exp[g * 128 + f]; }
            const float* wp = Wexp + (long long)g * 256 * 128 + f;
            float acc = bias;
            for (int c = 0; c < 256; ++c) acc += arow[c] * wp[c * 128];
            val = acc;
        }
        PTc[((long long)ck * 128 + f) * 24 + kl] = (bf16)val;
    }
}

// ---------------- z(dst) bucket sort ----------------

__global__ void k_zhist(const int* __restrict__ edst, const int* __restrict__ z,
                        int* __restrict__ zbins)
{
    __shared__ int h[NZ];
    for (int i = threadIdx.x; i < NZ; i += 256) h[i] = 0;
    __syncthreads();
    const int e = blockIdx.x * 256 + threadIdx.x;
    if (e < NEDGES) atomicAdd(&h[z[edst[e]]], 1);
    __syncthreads();
    for (int i = threadIdx.x; i < NZ; i += 256) if (h[i]) atomicAdd(&zbins[i], h[i]);
}

__global__ void k_zscan(const int* __restrict__ zbins, int* __restrict__ zcursor,
                        int* __restrict__ blk2z)
{
    __shared__ int st[NZ + 1];
    if (threadIdx.x == 0) {
        int s = 0;
        for (int zz = 0; zz < NZ; ++zz) {
            st[zz] = s; zcursor[zz] = s;
            s += ((zbins[zz] + 63) >> 6) << 6;       // 64-aligned buckets
        }
        st[NZ] = s;
    }
    __syncthreads();
    for (int b = threadIdx.x; b < NBLK; b += 256) blk2z[b] = 0;
    __syncthreads();
    if (threadIdx.x < NZ) {
        const int zz = threadIdx.x;
        for (int b = st[zz] >> 6; b < (st[zz + 1] >> 6); ++b) blk2z[b] = zz;
    }
}

__global__ void k_zfill(const int* __restrict__ edst, const int* __restrict__ z,
                        int* __restrict__ zcursor, int* __restrict__ perm)
{
    const int e = blockIdx.x * 256 + threadIdx.x;
    if (e < NEDGES) {
        const int pos = atomicAdd(&zcursor[z[edst[e]]], 1);
        perm[pos] = e;
    }
}

// ---------------- src CSR ----------------

__global__ void k_hist(const int* __restrict__ esrc, int* __restrict__ cnt)
{
    const int e = blockIdx.x * 256 + threadIdx.x;
    if (e < NEDGES) atomicAdd(&cnt[esrc[e]], 1);
}

__global__ void k_scan(const int* __restrict__ cnt, int* __restrict__ startp,
                       int* __restrict__ cursor, int n)
{
    __shared__ int part[1024];
    const int tid = threadIdx.x;
    const int chunk = (n + 1023) >> 10;
    const int lo = tid * chunk;
    const int hi = min(lo + chunk, n);
    int s = 0;
    for (int i = lo; i < hi; ++i) s += cnt[i];
    part[tid] = s;
    __syncthreads();
    for (int off = 1; off < 1024; off <<= 1) {
        int t = part[tid];
        if (tid >= off) t += part[tid - off];
        __syncthreads();
        part[tid] = t;
        __syncthreads();
    }
    int run = (tid == 0) ? 0 : part[tid - 1];
    for (int i = lo; i < hi; ++i) { startp[i] = run; cursor[i] = run; run += cnt[i]; }
}

__global__ void k_fill(const int* __restrict__ esrc, int* __restrict__ cursor,
                       int* __restrict__ csr)
{
    const int e = blockIdx.x * 256 + threadIdx.x;
    if (e < NEDGES) {
        const int pos = atomicAdd(&cursor[esrc[e]], 1);
        csr[pos] = e;
    }
}

// ---------------- MFMA edge kernel ----------------
// 64 edges/block, 4 waves. D[64x128] = w[64x608] @ PT[608x128] via 32x32x16 bf16 MFMA.
// K-chunks of 16: 37 from PTc (double-buffered LDS), final chunk = Hj[z_dst] rows
// (z_dst uniform per block thanks to the bucket sort; coeff = gate_g).
__global__ void __launch_bounds__(256) k_edge(
    const float* __restrict__ edge_vec,
    const int* __restrict__ perm, const int* __restrict__ blk2z,
    const float* __restrict__ tpar,
    const float* __restrict__ Hj,
    const bf16* __restrict__ PTc,
    float* __restrict__ gates_ws,
    float* __restrict__ evb,
    bf16* __restrict__ eo)
{
    __shared__ __align__(16) bf16 As[BE * APAD];        // 78848 B
    __shared__ __align__(16) bf16 Bdb[2][128 * 24];     // 12288 B
    __shared__ __align__(16) bf16 Bh[128 * 24];         //  6144 B
    __shared__ float sgate[NG][BE];
    __shared__ float ssv[6][BE];
    __shared__ float sC[BE];
    __shared__ int   seid[BE];
    __shared__ int   szb;

    const int tid  = threadIdx.x;
    const int lane = tid & 63;
    const int wid  = tid >> 6;

    // ---- phase 0: per-edge scalars (wave 0) ----
    if (tid == 0) szb = blk2z[blockIdx.x];
    if (tid < BE) {
        const int eid = perm[blockIdx.x * BE + tid];
        seid[tid] = eid;
        float sg[NG];
        float vx = 0.f, vy = 0.f, vz = 0.f, d = 1.0f, C = 0.f;
        if (eid >= 0) {
            vx = edge_vec[eid * 3]; vy = edge_vec[eid * 3 + 1]; vz = edge_vec[eid * 3 + 2];
            d = sqrtf(vx * vx + vy * vy + vz * vz);
            C = (d < 5.0f) ? 0.5f * (cosf(d * 0.6283185307179586f) + 1.0f) : 0.0f;
            float m = -3.0e38f;
#pragma unroll
            for (int g = 0; g < NG; ++g) {
                float r = 1.0f / fmaxf(fabsf(d - tpar[g]), 1e-8f);
                sg[g] = r; m = fmaxf(m, r);
            }
            float ss = 0.f;
#pragma unroll
            for (int g = 0; g < NG; ++g) { float ex = expf(sg[g] - m); sg[g] = ex; ss += ex; }
            const float inv = 1.0f / ss;
#pragma unroll
            for (int g = 0; g < NG; ++g) sg[g] *= inv;
        } else {
#pragma unroll
            for (int g = 0; g < NG; ++g) sg[g] = 0.f;
        }
#pragma unroll
        for (int g = 0; g < NG; ++g) sgate[g][tid] = sg[g];
        const float d2 = d * d;
        const float real = (eid >= 0) ? 1.0f : 0.0f;
        ssv[0][tid] = real * d2;
        ssv[1][tid] = real * d2 * d;
        ssv[2][tid] = real * d2 * d2;
        ssv[3][tid] = real * sqrtf(d);
        ssv[4][tid] = real * logf(d);
        ssv[5][tid] = real * d;          // doubles as 'd' for the rbf (0 for dummy is fine: gate=0,C=0)
        sC[tid] = C;
        if (eid >= 0) {
            const float invd = 1.0f / d;
            float* gw = gates_ws + (long long)eid * 12;
#pragma unroll
            for (int g = 0; g < NG; ++g) gw[g] = sg[g];
            gw[10] = 0.f; gw[11] = 0.f;
            evb[(long long)eid * 3 + 0] = vx * invd;
            evb[(long long)eid * 3 + 1] = vy * invd;
            evb[(long long)eid * 3 + 2] = vz * invd;
        }
    }
    __syncthreads();

    // ---- Bh fill (Hj chunk) + w-build + prefetch chunk 0 ----
    {
        const int zb = szb;
        for (int idx = tid; idx < 128 * 24; idx += 256) {
            const int f = idx / 24, kk = idx - (idx / 24) * 24;
            float v = (kk < NG) ? Hj[(long long)zb * 1280 + kk * 128 + f] : 0.0f;
            Bh[f * 24 + kk] = (bf16)v;
        }
    }
    {
        const int e = tid & 63;
        const int slice = tid >> 6;
        const float C = sC[e];
        const float d = ssv[5][e];
        const float DELTA = 5.0f / 49.0f;
        const float COEFF = -0.5f / (DELTA * DELTA);
        const int k0 = slice * 152;
        for (int kk = 0; kk < 152; ++kk) {
            const int k = k0 + kk;
            float val;
            if (k < 500) {
                const int g = k / 50, rb = k - (k / 50) * 50;
                const float t = d - (float)rb * DELTA;
                val = C * sgate[g][e] * expf(COEFF * t * t);
            } else if (k < 560) {
                const int jj = k - 500;
                const int g = jj / 6, m = jj - (jj / 6) * 6;
                val = sgate[g][e] * ssv[m][e];
            } else if (k < 570) { val = C * sgate[k - 560][e]; }
            else if (k < 580)  { val = sgate[k - 570][e]; }
            else if (k >= 592 && k < 602) { val = sgate[k - 592][e]; }
            else val = 0.0f;
            As[e * APAD + k] = (bf16)val;
        }
    }
    const float4* PTc4 = (const float4*)PTc;
    const bool has2 = (tid < 128);
    float4 st0a, st0b;
    st0a = PTc4[tid];
    if (has2) st0b = PTc4[256 + tid];
    __syncthreads();
    {
        float4* dst = (float4*)&Bdb[0][0];
        dst[tid] = st0a;
        if (has2) dst[256 + tid] = st0b;
    }
    __syncthreads();

    // ---- main MFMA loop ----
    const int eg  = wid & 1;
    const int ntb = (wid >> 1) * 2;
    const int arow = eg * 32 + (lane & 31);
    const int koff = (lane >> 5) * 8;
    const bf16* Ap = As + arow * APAD + koff;
    const int brow0 = (ntb * 32 + (lane & 31)) * 24 + koff;
    const int brow1 = brow0 + 32 * 24;

    f32x16 acc0 = {};
    f32x16 acc1 = {};

    for (int ks = 0; ks < KSTEPS; ++ks) {
        float4 sa, sb;
        const bool do_stage = (ks + 1 < NCHUNK_PT);
        if (do_stage) {
            const float4* src = PTc4 + (long long)(ks + 1) * 384;
            sa = src[tid];
            if (has2) sb = src[256 + tid];
        }
        const bf16* Bbase = (ks < NCHUNK_PT) ? &Bdb[ks & 1][0] : &Bh[0];
        const bf16x8 a  = *(const bf16x8*)(Ap + ks * 16);
        const bf16x8 b0 = *(const bf16x8*)(Bbase + brow0);
        const bf16x8 b1 = *(const bf16x8*)(Bbase + brow1);
        acc0 = __builtin_amdgcn_mfma_f32_32x32x16_bf16(a, b0, acc0, 0, 0, 0);
        acc1 = __builtin_amdgcn_mfma_f32_32x32x16_bf16(a, b1, acc1, 0, 0, 0);
        if (do_stage) {
            float4* dst = (float4*)&Bdb[(ks + 1) & 1][0];
            dst[tid] = sa;
            if (has2) dst[256 + tid] = sb;
        }
        __syncthreads();
    }

    // ---- epilogue: scatter rows to eo (original edge ids) ----
#pragma unroll
    for (int r = 0; r < 16; ++r) {
        const int erow = eg * 32 + (r & 3) + 8 * (r >> 2) + 4 * (lane >> 5);
        const int eid = seid[erow];
        if (eid >= 0) {
            eo[(long long)eid * 128 + ntb * 32 + (lane & 31)]       = (bf16)acc0[r];
            eo[(long long)eid * 128 + (ntb + 1) * 32 + (lane & 31)] = (bf16)acc1[r];
        }
    }
}

// ---------------- gather (+ exact Hi fold) ----------------

__global__ void __launch_bounds__(256) k_gather(
    const bf16* __restrict__ eo, const float* __restrict__ evb,
    const float* __restrict__ gates_ws,
    const int* __restrict__ startp, const int* __restrict__ cnt,
    const int* __restrict__ csr, const int* __restrict__ zarr,
    const float* __restrict__ Hi, float* __restrict__ out)
{
    const int atom = blockIdx.x * 4 + (threadIdx.x >> 6);
    const int lane = threadIdx.x & 63;
    if (atom >= NATOMS) return;
    const int s = startp[atom], len = cnt[atom];
    float a0 = 0, a1 = 0, v00 = 0, v01 = 0, v10 = 0, v11 = 0, v20 = 0, v21 = 0;
    float gs[NG] = {}, e0g[NG] = {}, e1g[NG] = {}, e2g[NG] = {};
    for (int i = 0; i < len; ++i) {
        const int eid = csr[s + i];
        const float evx = evb[(long long)eid * 3];
        const float evy = evb[(long long)eid * 3 + 1];
        const float evz = evb[(long long)eid * 3 + 2];
        const float4* gp = (const float4*)(gates_ws + (long long)eid * 12);
        const float4 q0 = gp[0], q1 = gp[1], q2 = gp[2];
        const float ga[NG] = {q0.x, q0.y, q0.z, q0.w, q1.x, q1.y, q1.z, q1.w, q2.x, q2.y};
#pragma unroll
        for (int g = 0; g < NG; ++g) {
            gs[g] += ga[g]; e0g[g] += evx * ga[g]; e1g[g] += evy * ga[g]; e2g[g] += evz * ga[g];
        }
        const float y0 = (float)eo[(long long)eid * 128 + lane];
        const float y1 = (float)eo[(long long)eid * 128 + 64 + lane];
        a0 += y0; a1 += y1;
        v00 += evx * y0; v01 += evx * y1;
        v10 += evy * y0; v11 += evy * y1;
        v20 += evz * y0; v21 += evz * y1;
    }
    const float* Hrow = Hi + (long long)zarr[atom] * 1280;
#pragma unroll
    for (int g = 0; g < NG; ++g) {
        const float h0 = Hrow[g * 128 + lane], h1 = Hrow[g * 128 + 64 + lane];
        a0  += gs[g] * h0;  a1  += gs[g] * h1;
        v00 += e0g[g] * h0; v01 += e0g[g] * h1;
        v10 += e1g[g] * h0; v11 += e1g[g] * h1;
        v20 += e2g[g] * h0; v21 += e2g[g] * h1;
    }
    float* ao = out + (long long)atom * 128;
    ao[lane] = a0; ao[64 + lane] = a1;
    float* vp = out + OUT_VEC + (long long)atom * 384;
    vp[lane] = v00;        vp[64 + lane] = v01;
    vp[128 + lane] = v10;  vp[192 + lane] = v11;
    vp[256 + lane] = v20;  vp[320 + lane] = v21;
}

__global__ void k_tail(const int* __restrict__ z, const float* __restrict__ pos,
                       const int* __restrict__ batch, float* __restrict__ out)
{
    const int i = blockIdx.x * 256 + threadIdx.x;
    if (i < NATOMS) {
        out[OUT_Z + i] = (float)z[i];
        out[OUT_BATCH + i] = (float)batch[i];
    }
    if (i < 3 * NATOMS) out[OUT_POS + i] = pos[i];
}

// ---------------- launch ----------------

extern "C" void kernel_launch(void* const* d_in, const int* in_sizes, int n_in,
                              void* d_out, int out_size, void* d_ws, size_t ws_size,
                              hipStream_t stream)
{
    const int*   z        = (const int*)d_in[0];
    const float* pos      = (const float*)d_in[1];
    const int*   batch    = (const int*)d_in[2];
    const int*   esrc     = (const int*)d_in[3];
    const int*   edst     = esrc + NEDGES;
    const float* edge_vec = (const float*)d_in[4];
    const float* emb      = (const float*)d_in[5];
    const float* W_dist   = (const float*)d_in[6];
    const float* b_dist   = (const float*)d_in[7];
    const float* W_dt     = (const float*)d_in[8];
    const float* b_dt     = (const float*)d_in[9];
    const float* W_ai     = (const float*)d_in[10];
    const float* b_ai     = (const float*)d_in[11];
    const float* W_aj     = (const float*)d_in[12];
    const float* b_aj     = (const float*)d_in[13];
    const float* W_gamma  = (const float*)d_in[14];
    const float* b_gamma  = (const float*)d_in[15];
    const float* W_exp    = (const float*)d_in[16];
    const float* b_exp    = (const float*)d_in[17];
    const float* tpar     = (const float*)d_in[18];

    float* out = (float*)d_out;
    float* W   = (float*)d_ws;

    const float* Wg1 = W_gamma;
    const float* Wg2 = W_gamma + 256 * 256;
    const float* Wg3 = W_gamma + 512 * 256;

    float* M1 = W + WS_M1;
    float* M0 = W + WS_M0;
    float* c0 = W + WS_C0;
    float* M2 = W + WS_M2;
    float* cc = W + WS_CC;
    float* Ai = W + WS_AI;
    float* Aj = W + WS_AJ;
    float* Gi = W + WS_GI;
    float* Gj = W + WS_GJ;
    float* Hi = W + WS_HI;
    float* Hj = W + WS_HJ;
    bf16*  PTc = (bf16*)(W + WS_PTC);
    float* gates = W + WS_GT;
    float* evb   = W + WS_EV;
    bf16*  eo    = (bf16*)(W + WS_EO);
    int*   I     = (int*)(W + WS_I);
    int* cnt    = I + I_CNT;
    int* startp = I + I_START;
    int* cursor = I + I_CUR;
    int* csr    = I + I_CSR;
    int* zbins  = I + I_ZB;
    int* zcur   = I + I_ZC;
    int* perm   = I + I_PERM;
    int* b2z    = I + I_B2Z;

    // precompute chain
    k_mm256<<<256, 256, 0, stream>>>(W_dt, 256, Wg3, nullptr, M1, 256);
    k_mm256<<<50,  256, 0, stream>>>(W_dist, 256, M1, nullptr, M0, 256);
    k_mm256<<<1,   256, 0, stream>>>(b_dist, 0, M1, nullptr, c0, 256);
    k_mm256<<<6,   256, 0, stream>>>(W_dt + 256 * 256, 256, Wg3, nullptr, M2, 256);
    k_mm256<<<1,   256, 0, stream>>>(b_dt, 0, Wg3, b_gamma, cc, 256);
    k_mm256<<<100, 256, 0, stream>>>(emb, 256, W_ai, b_ai, Ai, 256);
    k_mm256<<<100, 256, 0, stream>>>(emb, 256, W_aj, b_aj, Aj, 256);
    k_mm256<<<100, 256, 0, stream>>>(Ai, 256, Wg1, nullptr, Gi, 256);
    k_mm256<<<100, 256, 0, stream>>>(Aj, 256, Wg2, nullptr, Gj, 256);
    k_htable<<<1000, 128, 0, stream>>>(Gi, W_exp, Hi);
    k_htable<<<1000, 128, 0, stream>>>(Gj, W_exp, Hj);
    k_ptc<<<NCHUNK_PT, 128, 0, stream>>>(M0, M2, c0, cc, W_exp, b_exp, PTc);

    hipMemsetAsync(cnt, 0, NATOMS * sizeof(int), stream);
    hipMemsetAsync(zbins, 0, 128 * sizeof(int), stream);
    hipMemsetAsync(perm, 0xFF, NBLK * 64 * sizeof(int), stream);

    k_zhist<<<(NEDGES + 255) / 256, 256, 0, stream>>>(edst, z, zbins);
    k_zscan<<<1, 256, 0, stream>>>(zbins, zcur, b2z);
    k_zfill<<<(NEDGES + 255) / 256, 256, 0, stream>>>(edst, z, zcur, perm);
    k_hist<<<(NEDGES + 255) / 256, 256, 0, stream>>>(esrc, cnt);
    k_scan<<<1, 1024, 0, stream>>>(cnt, startp, cursor, NATOMS);
    k_fill<<<(NEDGES + 255) / 256, 256, 0, stream>>>(esrc, cursor, csr);

    k_edge<<<NBLK, 256, 0, stream>>>(edge_vec, perm, b2z, tpar, Hj, PTc, gates, evb, eo);
    k_gather<<<(NATOMS + 3) / 4, 256, 0, stream>>>(eo, evb, gates, startp, cnt, csr, z, Hi, out);
    k_tail<<<(3 * NATOMS + 255) / 256, 256, 0, stream>>>(z, pos, batch, out);
}

// Round 3
// 1073.663 us; speedup vs baseline: 2.4206x; 1.9287x over previous
//
#include <hip/hip_runtime.h>
#include <math.h>

typedef __bf16 bf16;
typedef __bf16 bf16x8 __attribute__((ext_vector_type(8)));
typedef float  f32x16 __attribute__((ext_vector_type(16)));

#define NATOMS 50000
#define NEDGES 400000
#define NG 10
#define NZ 100
#define BE 64
#define NBLK 6350
#define KSTEPS 38
#define DELTA_F 0.10204081632653061f          /* 5/49 */
#define C2T (-48.02f * 1.4426950408889634f)   /* (-0.5/DELTA^2)*log2(e) */

#if defined(__has_builtin)
#  if __has_builtin(__builtin_amdgcn_exp2f)
#    define EXP2F(x) __builtin_amdgcn_exp2f(x)
#  else
#    define EXP2F(x) exp2f(x)
#  endif
#else
#  define EXP2F(x) exp2f(x)
#endif

// ---- d_out layout (float elements) ----
#define OUT_VEC   6400000LL
#define OUT_Z     25600000LL
#define OUT_POS   25650000LL
#define OUT_BATCH 25800000LL

// ---- workspace layout (float units) ----
#define WS_M1   0LL
#define WS_M0   65536LL
#define WS_C0   78336LL
#define WS_M2   78592LL
#define WS_CC   80128LL
#define WS_AI   80384LL
#define WS_AJ   105984LL
#define WS_GI   131584LL
#define WS_GJ   157184LL
#define WS_HI   182784LL          /* 100*10*128 f32 */
#define WS_HJB  310784LL          /* 100*2048 bf16 = 102400 fu */
#define WS_PTC  413184LL          /* 37*2048 bf16 = 37888 fu */
#define WS_GT   451072LL          /* [406400][12] f32 */
#define WS_EV   5327872LL         /* [406400][3] f32 */
#define WS_EO   6547072LL         /* [406400][128] bf16 = 26009600 fu */
#define WS_I    32556672LL        /* int region */
// int region offsets (ints)
#define I_CNT   0
#define I_START 50000
#define I_CUR   100000
#define I_CSR   150000
#define I_ZB    550000
#define I_ZC    550128
#define I_B2Z   550256
#define I_PERM  556608            /* NBLK*64 = 406400 */
#define I_INVP  963008            /* NEDGES */

// ---------------- ILP dot helpers ----------------

__device__ __forceinline__ float dot256(const float* __restrict__ a,
                                        const float* __restrict__ B, int c)
{
    float s0 = 0, s1 = 0, s2 = 0, s3 = 0;
    for (int k = 0; k < 256; k += 4) {
        s0 += a[k]     * B[(k)     * 256 + c];
        s1 += a[k + 1] * B[(k + 1) * 256 + c];
        s2 += a[k + 2] * B[(k + 2) * 256 + c];
        s3 += a[k + 3] * B[(k + 3) * 256 + c];
    }
    return (s0 + s1) + (s2 + s3);
}

// ---------------- precompute kernels ----------------

__global__ void k_pre_dt(const float* __restrict__ W_dt, const float* __restrict__ b_dt,
                         const float* __restrict__ b_gamma, const float* __restrict__ Wg3,
                         float* __restrict__ M1, float* __restrict__ M2, float* __restrict__ cc)
{
    const int r = blockIdx.x, c = threadIdx.x;     // grid 263
    const float* a = (r < 262) ? (W_dt + (size_t)r * 256) : b_dt;
    float res = dot256(a, Wg3, c);
    if (r == 262) res += b_gamma[c];
    if (r < 256) M1[(size_t)r * 256 + c] = res;
    else if (r < 262) M2[(size_t)(r - 256) * 256 + c] = res;
    else cc[c] = res;
}

__global__ void k_pre_emb(const float* __restrict__ emb,
                          const float* __restrict__ W_ai, const float* __restrict__ b_ai,
                          const float* __restrict__ W_aj, const float* __restrict__ b_aj,
                          float* __restrict__ Ai, float* __restrict__ Aj)
{
    const int r = blockIdx.x, c = threadIdx.x;     // grid 200
    const int zz = r % 100, side = r / 100;
    float res = dot256(emb + (size_t)zz * 256, side ? W_aj : W_ai, c)
              + (side ? b_aj[c] : b_ai[c]);
    (side ? Aj : Ai)[(size_t)zz * 256 + c] = res;
}

__global__ void k_pre_m0(const float* __restrict__ W_dist, const float* __restrict__ b_dist,
                         const float* __restrict__ M1, float* __restrict__ M0, float* __restrict__ c0)
{
    const int r = blockIdx.x, c = threadIdx.x;     // grid 51
    const float* a = (r < 50) ? (W_dist + (size_t)r * 256) : b_dist;
    float res = dot256(a, M1, c);
    if (r < 50) M0[(size_t)r * 256 + c] = res; else c0[c] = res;
}

__global__ void k_pre_g(const float* __restrict__ Ai, const float* __restrict__ Aj,
                        const float* __restrict__ Wg1, const float* __restrict__ Wg2,
                        float* __restrict__ Gi, float* __restrict__ Gj)
{
    const int r = blockIdx.x, c = threadIdx.x;     // grid 200
    const int zz = r % 100, side = r / 100;
    float res = side ? dot256(Aj + (size_t)zz * 256, Wg2, c)
                     : dot256(Ai + (size_t)zz * 256, Wg1, c);
    (side ? Gj : Gi)[(size_t)zz * 256 + c] = res;
}

__global__ void k_htable(const float* __restrict__ Gi, const float* __restrict__ Gj,
                         const float* __restrict__ Wexp,
                         float* __restrict__ Hi, bf16* __restrict__ Hjb)
{
    const int zg = blockIdx.x;                     // grid 1000
    const int zz = zg / 10, g = zg - zz * 10;
    const int f = threadIdx.x;                     // 128
    const float* w  = Wexp + (size_t)g * 32768 + f;
    const float* gi = Gi + (size_t)zz * 256;
    const float* gj = Gj + (size_t)zz * 256;
    float a0=0,a1=0,a2=0,a3=0,b0=0,b1=0,b2=0,b3=0;
    for (int k = 0; k < 256; k += 4) {
        const float w0 = w[k*128], w1 = w[(k+1)*128], w2 = w[(k+2)*128], w3 = w[(k+3)*128];
        a0 += gi[k]*w0;   a1 += gi[k+1]*w1; a2 += gi[k+2]*w2; a3 += gi[k+3]*w3;
        b0 += gj[k]*w0;   b1 += gj[k+1]*w1; b2 += gj[k+2]*w2; b3 += gj[k+3]*w3;
    }
    Hi[(size_t)zg * 128 + f] = (a0+a1)+(a2+a3);
    Hjb[(size_t)zz * 2048 + (g >> 3) * 1024 + f * 8 + (g & 7)] = (bf16)((b0+b1)+(b2+b3));
}

// PTc[ck][kh][f][8] bf16: element = PT[k=ck*16+kh*8+j][f]
__global__ void k_ptc(const float* __restrict__ M0, const float* __restrict__ M2,
                      const float* __restrict__ c0, const float* __restrict__ cc,
                      const float* __restrict__ Wexp, const float* __restrict__ b_exp,
                      bf16* __restrict__ PTc)
{
    const int b = blockIdx.x;                      // grid 592 = 37*16
    const int ck = b >> 4, kl = b & 15;
    const int f = threadIdx.x;                     // 128
    const int k = ck * 16 + kl;
    float val = 0.f;
    if (k < 580) {
        const float* arow; int g; float bias = 0.f;
        if (k < 500)      { g = k / 50; arow = M0 + (size_t)(k - g * 50) * 256; }
        else if (k < 560) { const int jj = k - 500; g = jj / 6; arow = M2 + (size_t)(jj - g * 6) * 256; }
        else if (k < 570) { g = k - 560; arow = c0; }
        else              { g = k - 570; arow = cc; bias = b_exp[g * 128 + f]; }
        const float* w = Wexp + (size_t)g * 32768 + f;
        float s0=0,s1=0,s2=0,s3=0;
        for (int c2 = 0; c2 < 256; c2 += 4) {
            s0 += arow[c2]   * w[(c2)   * 128];
            s1 += arow[c2+1] * w[(c2+1) * 128];
            s2 += arow[c2+2] * w[(c2+2) * 128];
            s3 += arow[c2+3] * w[(c2+3) * 128];
        }
        val = (s0+s1)+(s2+s3) + bias;
    }
    PTc[(size_t)ck * 2048 + (kl >> 3) * 1024 + f * 8 + (kl & 7)] = (bf16)val;
}

// ---------------- z(dst) bucket sort + src CSR ----------------

__global__ void k_zhist(const int* __restrict__ edst, const int* __restrict__ z,
                        int* __restrict__ zbins)
{
    __shared__ int h[NZ];
    for (int i = threadIdx.x; i < NZ; i += 256) h[i] = 0;
    __syncthreads();
    const int e = blockIdx.x * 256 + threadIdx.x;
    if (e < NEDGES) atomicAdd(&h[z[edst[e]]], 1);
    __syncthreads();
    for (int i = threadIdx.x; i < NZ; i += 256) if (h[i]) atomicAdd(&zbins[i], h[i]);
}

__global__ void k_zscan(const int* __restrict__ zbins, int* __restrict__ zcursor,
                        int* __restrict__ blk2z)
{
    __shared__ int st[NZ + 1];
    if (threadIdx.x == 0) {
        int s = 0;
        for (int zz = 0; zz < NZ; ++zz) {
            st[zz] = s; zcursor[zz] = s;
            s += ((zbins[zz] + 63) >> 6) << 6;
        }
        st[NZ] = s;
    }
    __syncthreads();
    for (int b = threadIdx.x; b < NBLK; b += 256) blk2z[b] = 0;
    __syncthreads();
    if (threadIdx.x < NZ) {
        const int zz = threadIdx.x;
        for (int b = st[zz] >> 6; b < (st[zz + 1] >> 6); ++b) blk2z[b] = zz;
    }
}

__global__ void k_zfill(const int* __restrict__ edst, const int* __restrict__ z,
                        int* __restrict__ zcursor, int* __restrict__ perm,
                        int* __restrict__ invp)
{
    const int e = blockIdx.x * 256 + threadIdx.x;
    if (e < NEDGES) {
        const int pos = atomicAdd(&zcursor[z[edst[e]]], 1);
        perm[pos] = e;
        invp[e] = pos;
    }
}

__global__ void k_hist(const int* __restrict__ esrc, int* __restrict__ cnt)
{
    const int e = blockIdx.x * 256 + threadIdx.x;
    if (e < NEDGES) atomicAdd(&cnt[esrc[e]], 1);
}

__global__ void k_scan(const int* __restrict__ cnt, int* __restrict__ startp,
                       int* __restrict__ cursor, int n)
{
    __shared__ int part[1024];
    const int tid = threadIdx.x;
    const int chunk = (n + 1023) >> 10;
    const int lo = tid * chunk;
    const int hi = min(lo + chunk, n);
    int s = 0;
    for (int i = lo; i < hi; ++i) s += cnt[i];
    part[tid] = s;
    __syncthreads();
    for (int off = 1; off < 1024; off <<= 1) {
        int t = part[tid];
        if (tid >= off) t += part[tid - off];
        __syncthreads();
        part[tid] = t;
        __syncthreads();
    }
    int run = (tid == 0) ? 0 : part[tid - 1];
    for (int i = lo; i < hi; ++i) { startp[i] = run; cursor[i] = run; run += cnt[i]; }
}

// csr stores PERMUTED ids (invp[e]) so gather indexes eo/evb/gates directly
__global__ void k_fill(const int* __restrict__ esrc, const int* __restrict__ invp,
                       int* __restrict__ cursor, int* __restrict__ csr)
{
    const int e = blockIdx.x * 256 + threadIdx.x;
    if (e < NEDGES) {
        const int pos = atomicAdd(&cursor[esrc[e]], 1);
        csr[pos] = invp[e];
    }
}

// ---------------- MFMA edge kernel (no LDS, no barriers) ----------------

__device__ __forceinline__ float coeff_one(int k, float d, const float* gate,
                                           const float* Cg, const float* sv)
{
    if (k < 500) {
        const int g = k / 50;
        const float t = d - (float)(k - g * 50) * DELTA_F;
        return Cg[g] * EXP2F(C2T * t * t);
    } else if (k < 560) {
        const int jj = k - 500;
        return gate[jj / 6] * sv[jj - (jj / 6) * 6];
    } else if (k < 570) {
        return Cg[k - 560];
    } else if (k < 580) {
        return gate[k - 570];
    }
    return 0.0f;
}

__global__ void __launch_bounds__(128) k_edge(
    const float* __restrict__ edge_vec,
    const int* __restrict__ perm, const int* __restrict__ blk2z,
    const float* __restrict__ tpar,
    const bf16* __restrict__ PTc, const bf16* __restrict__ Hjb,
    float* __restrict__ gates_ws, float* __restrict__ evb, bf16* __restrict__ eo)
{
    const int tid  = threadIdx.x;
    const int wid  = tid >> 6;
    const int lane = tid & 63;
    const int er   = lane & 31;
    const int kh   = lane >> 5;
    const bool khb = (kh != 0);
    const int pid  = blockIdx.x * BE + wid * 32 + er;
    const int eid  = perm[pid];
    const int zb   = blk2z[blockIdx.x];

    float gate[NG], Cg[NG], sv[6];
    float d = 1.0f, C = 0.0f, vx = 0.f, vy = 0.f, vz = 0.f;
    if (eid >= 0) {
        vx = edge_vec[eid * 3]; vy = edge_vec[eid * 3 + 1]; vz = edge_vec[eid * 3 + 2];
        d = sqrtf(vx * vx + vy * vy + vz * vz);
        C = (d < 5.0f) ? 0.5f * (__cosf(d * 0.6283185307179586f) + 1.0f) : 0.0f;
        float m = -3.0e38f;
#pragma unroll
        for (int g = 0; g < NG; ++g) {
            float r = 1.0f / fmaxf(fabsf(d - tpar[g]), 1e-8f);
            gate[g] = r; m = fmaxf(m, r);
        }
        float ss = 0.f;
#pragma unroll
        for (int g = 0; g < NG; ++g) { float ex = __expf(gate[g] - m); gate[g] = ex; ss += ex; }
        const float inv = 1.0f / ss;
#pragma unroll
        for (int g = 0; g < NG; ++g) gate[g] *= inv;
        const float d2 = d * d;
        sv[0] = d2; sv[1] = d2 * d; sv[2] = d2 * d2;
        sv[3] = sqrtf(d); sv[4] = __logf(d); sv[5] = d;
    } else {
#pragma unroll
        for (int g = 0; g < NG; ++g) gate[g] = 0.f;
#pragma unroll
        for (int m = 0; m < 6; ++m) sv[m] = 0.f;
    }
#pragma unroll
    for (int g = 0; g < NG; ++g) Cg[g] = C * gate[g];

    if (kh == 0 && eid >= 0) {
        float* gw = gates_ws + (size_t)pid * 12;
#pragma unroll
        for (int g = 0; g < NG; ++g) gw[g] = gate[g];
        const float invd = 1.0f / d;
        evb[(size_t)pid * 3 + 0] = vx * invd;
        evb[(size_t)pid * 3 + 1] = vy * invd;
        evb[(size_t)pid * 3 + 2] = vz * invd;
    }

    const float dsh = d - (khb ? 8.0f * DELTA_F : 0.0f);
    const int lanoff = kh * 1024 + er * 8;
    const bf16* __restrict__ Bpt = PTc + lanoff;
    const bf16* __restrict__ Bhj = Hjb + (size_t)zb * 2048 + lanoff;

    f32x16 acc0 = {}, acc1 = {}, acc2 = {}, acc3 = {};

#pragma unroll
    for (int ks = 0; ks < KSTEPS; ++ks) {
        bf16x8 av;
        if (ks < 31) {
            // both halves rbf: share the exp via dsh
#pragma unroll
            for (int j = 0; j < 8; ++j) {
                const int kA = ks * 16 + j;
                const int gA = kA / 50, gB = (kA + 8) / 50;
                const float t = dsh - (float)kA * DELTA_F;
                const float e = EXP2F(C2T * t * t);
                const float mm = (gA == gB) ? Cg[gA] : (khb ? Cg[gB] : Cg[gA]);
                av[j] = (bf16)(mm * e);
            }
        } else if (ks < 37) {
#pragma unroll
            for (int j = 0; j < 8; ++j) {
                const int kA = ks * 16 + j;
                const float va = coeff_one(kA, d, gate, Cg, sv);
                const float vb = coeff_one(kA + 8, d, gate, Cg, sv);
                av[j] = (bf16)(khb ? vb : va);
            }
        } else {
            // Hj chunk: coeff = gate[k_local]
#pragma unroll
            for (int j = 0; j < 8; ++j) {
                const float va = gate[j];
                const float vb = (j < 2) ? gate[8 + j] : 0.0f;
                av[j] = (bf16)(khb ? vb : va);
            }
        }
        const bf16* bp = (ks < 37) ? (Bpt + ks * 2048) : Bhj;
        const bf16x8 b0 = *(const bf16x8*)(bp);
        const bf16x8 b1 = *(const bf16x8*)(bp + 256);
        const bf16x8 b2 = *(const bf16x8*)(bp + 512);
        const bf16x8 b3 = *(const bf16x8*)(bp + 768);
        acc0 = __builtin_amdgcn_mfma_f32_32x32x16_bf16(av, b0, acc0, 0, 0, 0);
        acc1 = __builtin_amdgcn_mfma_f32_32x32x16_bf16(av, b1, acc1, 0, 0, 0);
        acc2 = __builtin_amdgcn_mfma_f32_32x32x16_bf16(av, b2, acc2, 0, 0, 0);
        acc3 = __builtin_amdgcn_mfma_f32_32x32x16_bf16(av, b3, acc3, 0, 0, 0);
    }

    // epilogue: rows are block-local pids -> unconditional coalesced-ish stores
    bf16* eor = eo + ((size_t)(blockIdx.x * BE + wid * 32) * 128) + er;
#pragma unroll
    for (int r = 0; r < 16; ++r) {
        const int crow = (r & 3) + 8 * (r >> 2) + 4 * kh;
        bf16* p = eor + (size_t)crow * 128;
        p[0]  = (bf16)acc0[r];
        p[32] = (bf16)acc1[r];
        p[64] = (bf16)acc2[r];
        p[96] = (bf16)acc3[r];
    }
}

// ---------------- gather (+ exact Hi fold) ----------------

__global__ void __launch_bounds__(256) k_gather(
    const bf16* __restrict__ eo, const float* __restrict__ evb,
    const float* __restrict__ gates_ws,
    const int* __restrict__ startp, const int* __restrict__ cnt,
    const int* __restrict__ csr, const int* __restrict__ zarr,
    const float* __restrict__ Hi, float* __restrict__ out)
{
    const int atom = blockIdx.x * 4 + (threadIdx.x >> 6);
    const int lane = threadIdx.x & 63;
    if (atom >= NATOMS) return;
    const int s = startp[atom], len = cnt[atom];
    float a0 = 0, a1 = 0, v00 = 0, v01 = 0, v10 = 0, v11 = 0, v20 = 0, v21 = 0;
    float gs[NG] = {}, e0g[NG] = {}, e1g[NG] = {}, e2g[NG] = {};
    for (int i = 0; i < len; ++i) {
        const int pid = csr[s + i];
        const float evx = evb[(size_t)pid * 3];
        const float evy = evb[(size_t)pid * 3 + 1];
        const float evz = evb[(size_t)pid * 3 + 2];
        const float4* gp = (const float4*)(gates_ws + (size_t)pid * 12);
        const float4 q0 = gp[0], q1 = gp[1], q2 = gp[2];
        const float ga[NG] = {q0.x, q0.y, q0.z, q0.w, q1.x, q1.y, q1.z, q1.w, q2.x, q2.y};
#pragma unroll
        for (int g = 0; g < NG; ++g) {
            gs[g] += ga[g]; e0g[g] += evx * ga[g]; e1g[g] += evy * ga[g]; e2g[g] += evz * ga[g];
        }
        const float y0 = (float)eo[(size_t)pid * 128 + lane];
        const float y1 = (float)eo[(size_t)pid * 128 + 64 + lane];
        a0 += y0; a1 += y1;
        v00 += evx * y0; v01 += evx * y1;
        v10 += evy * y0; v11 += evy * y1;
        v20 += evz * y0; v21 += evz * y1;
    }
    const float* Hrow = Hi + (size_t)zarr[atom] * 1280;
#pragma unroll
    for (int g = 0; g < NG; ++g) {
        const float h0 = Hrow[g * 128 + lane], h1 = Hrow[g * 128 + 64 + lane];
        a0  += gs[g] * h0;  a1  += gs[g] * h1;
        v00 += e0g[g] * h0; v01 += e0g[g] * h1;
        v10 += e1g[g] * h0; v11 += e1g[g] * h1;
        v20 += e2g[g] * h0; v21 += e2g[g] * h1;
    }
    float* ao = out + (size_t)atom * 128;
    ao[lane] = a0; ao[64 + lane] = a1;
    float* vp = out + OUT_VEC + (size_t)atom * 384;
    vp[lane] = v00;        vp[64 + lane] = v01;
    vp[128 + lane] = v10;  vp[192 + lane] = v11;
    vp[256 + lane] = v20;  vp[320 + lane] = v21;
}

__global__ void k_tail(const int* __restrict__ z, const float* __restrict__ pos,
                       const int* __restrict__ batch, float* __restrict__ out)
{
    const int i = blockIdx.x * 256 + threadIdx.x;
    if (i < NATOMS) {
        out[OUT_Z + i] = (float)z[i];
        out[OUT_BATCH + i] = (float)batch[i];
    }
    if (i < 3 * NATOMS) out[OUT_POS + i] = pos[i];
}

// ---------------- launch ----------------

extern "C" void kernel_launch(void* const* d_in, const int* in_sizes, int n_in,
                              void* d_out, int out_size, void* d_ws, size_t ws_size,
                              hipStream_t stream)
{
    const int*   z        = (const int*)d_in[0];
    const float* pos      = (const float*)d_in[1];
    const int*   batch    = (const int*)d_in[2];
    const int*   esrc     = (const int*)d_in[3];
    const int*   edst     = esrc + NEDGES;
    const float* edge_vec = (const float*)d_in[4];
    const float* emb      = (const float*)d_in[5];
    const float* W_dist   = (const float*)d_in[6];
    const float* b_dist   = (const float*)d_in[7];
    const float* W_dt     = (const float*)d_in[8];
    const float* b_dt     = (const float*)d_in[9];
    const float* W_ai     = (const float*)d_in[10];
    const float* b_ai     = (const float*)d_in[11];
    const float* W_aj     = (const float*)d_in[12];
    const float* b_aj     = (const float*)d_in[13];
    const float* W_gamma  = (const float*)d_in[14];
    const float* b_gamma  = (const float*)d_in[15];
    const float* W_exp    = (const float*)d_in[16];
    const float* b_exp    = (const float*)d_in[17];
    const float* tpar     = (const float*)d_in[18];

    float* out = (float*)d_out;
    float* W   = (float*)d_ws;

    const float* Wg1 = W_gamma;
    const float* Wg2 = W_gamma + 256 * 256;
    const float* Wg3 = W_gamma + 512 * 256;

    float* M1 = W + WS_M1;
    float* M0 = W + WS_M0;
    float* c0 = W + WS_C0;
    float* M2 = W + WS_M2;
    float* cc = W + WS_CC;
    float* Ai = W + WS_AI;
    float* Aj = W + WS_AJ;
    float* Gi = W + WS_GI;
    float* Gj = W + WS_GJ;
    float* Hi = W + WS_HI;
    bf16*  Hjb = (bf16*)(W + WS_HJB);
    bf16*  PTc = (bf16*)(W + WS_PTC);
    float* gates = W + WS_GT;
    float* evb   = W + WS_EV;
    bf16*  eo    = (bf16*)(W + WS_EO);
    int*   I     = (int*)(W + WS_I);
    int* cnt    = I + I_CNT;
    int* startp = I + I_START;
    int* cursor = I + I_CUR;
    int* csr    = I + I_CSR;
    int* zbins  = I + I_ZB;
    int* zcur   = I + I_ZC;
    int* b2z    = I + I_B2Z;
    int* perm   = I + I_PERM;
    int* invp   = I + I_INVP;

    // precompute chain
    k_pre_dt<<<263, 256, 0, stream>>>(W_dt, b_dt, b_gamma, Wg3, M1, M2, cc);
    k_pre_emb<<<200, 256, 0, stream>>>(emb, W_ai, b_ai, W_aj, b_aj, Ai, Aj);
    k_pre_m0<<<51, 256, 0, stream>>>(W_dist, b_dist, M1, M0, c0);
    k_pre_g<<<200, 256, 0, stream>>>(Ai, Aj, Wg1, Wg2, Gi, Gj);
    hipMemsetAsync(Hjb, 0, 100 * 2048 * sizeof(bf16), stream);
    k_htable<<<1000, 128, 0, stream>>>(Gi, Gj, W_exp, Hi, Hjb);
    k_ptc<<<592, 128, 0, stream>>>(M0, M2, c0, cc, W_exp, b_exp, PTc);

    hipMemsetAsync(cnt, 0, NATOMS * sizeof(int), stream);
    hipMemsetAsync(zbins, 0, 128 * sizeof(int), stream);
    hipMemsetAsync(perm, 0xFF, NBLK * 64 * sizeof(int), stream);

    k_zhist<<<(NEDGES + 255) / 256, 256, 0, stream>>>(edst, z, zbins);
    k_zscan<<<1, 256, 0, stream>>>(zbins, zcur, b2z);
    k_zfill<<<(NEDGES + 255) / 256, 256, 0, stream>>>(edst, z, zcur, perm, invp);
    k_hist<<<(NEDGES + 255) / 256, 256, 0, stream>>>(esrc, cnt);
    k_scan<<<1, 1024, 0, stream>>>(cnt, startp, cursor, NATOMS);
    k_fill<<<(NEDGES + 255) / 256, 256, 0, stream>>>(esrc, invp, cursor, csr);

    k_edge<<<NBLK, 128, 0, stream>>>(edge_vec, perm, b2z, tpar, PTc, Hjb, gates, evb, eo);
    k_gather<<<(NATOMS + 3) / 4, 256, 0, stream>>>(eo, evb, gates, startp, cnt, csr, z, Hi, out);
    k_tail<<<(3 * NATOMS + 255) / 256, 256, 0, stream>>>(z, pos, batch, out);
}

// Round 4
// 674.020 us; speedup vs baseline: 3.8558x; 1.5929x over previous
//
#include <hip/hip_runtime.h>
#include <math.h>

typedef __bf16 bf16;
typedef __bf16 bf16x8 __attribute__((ext_vector_type(8)));
typedef float  f32x16 __attribute__((ext_vector_type(16)));

#define NATOMS 50000
#define NEDGES 400000
#define NG 10
#define NZ 100
#define BE 64
#define NBLK 6350
#define KSTEPS 38
#define DELTA_F 0.10204081632653061f          /* 5/49 */
#define C2T (-48.02f * 1.4426950408889634f)   /* (-0.5/DELTA^2)*log2(e) */

#if defined(__has_builtin)
#  if __has_builtin(__builtin_amdgcn_exp2f)
#    define EXP2F(x) __builtin_amdgcn_exp2f(x)
#  else
#    define EXP2F(x) exp2f(x)
#  endif
#else
#  define EXP2F(x) exp2f(x)
#endif

// ---- d_out layout (float elements) ----
#define OUT_VEC   6400000LL
#define OUT_Z     25600000LL
#define OUT_POS   25650000LL
#define OUT_BATCH 25800000LL

// ---- workspace layout (float units) ----
#define WS_M1   0LL
#define WS_M0   65536LL
#define WS_C0   78336LL
#define WS_M2   78592LL
#define WS_CC   80128LL
#define WS_AI   80384LL
#define WS_AJ   105984LL
#define WS_GI   131584LL
#define WS_GJ   157184LL
#define WS_HI   182784LL          /* 100*10*128 f32 */
#define WS_HJB  310784LL          /* 100*2048 bf16 = 102400 fu */
#define WS_PTC  413184LL          /* 37*2048 bf16 = 37888 fu */
#define WS_GT   451072LL          /* [406400][12] f32 */
#define WS_EV   5327872LL         /* [406400][3] f32 */
#define WS_EO   6547072LL         /* [406400][128] bf16 = 26009600 fu */
#define WS_I    32556672LL        /* int region */
// int region offsets (ints)
#define I_CNT   0
#define I_START 50000
#define I_CUR   100000
#define I_CSR   150000
#define I_ZB    550000
#define I_ZC    550128
#define I_B2Z   550256
#define I_PERM  556608            /* NBLK*64 = 406400 */

// ---------------- ILP dot helpers ----------------

__device__ __forceinline__ float dot256(const float* __restrict__ a,
                                        const float* __restrict__ B, int c)
{
    float s0 = 0, s1 = 0, s2 = 0, s3 = 0;
    for (int k = 0; k < 256; k += 4) {
        s0 += a[k]     * B[(k)     * 256 + c];
        s1 += a[k + 1] * B[(k + 1) * 256 + c];
        s2 += a[k + 2] * B[(k + 2) * 256 + c];
        s3 += a[k + 3] * B[(k + 3) * 256 + c];
    }
    return (s0 + s1) + (s2 + s3);
}

// ---------------- precompute kernels ----------------

__global__ void k_pre_dt(const float* __restrict__ W_dt, const float* __restrict__ b_dt,
                         const float* __restrict__ b_gamma, const float* __restrict__ Wg3,
                         float* __restrict__ M1, float* __restrict__ M2, float* __restrict__ cc)
{
    const int r = blockIdx.x, c = threadIdx.x;     // grid 263
    const float* a = (r < 262) ? (W_dt + (size_t)r * 256) : b_dt;
    float res = dot256(a, Wg3, c);
    if (r == 262) res += b_gamma[c];
    if (r < 256) M1[(size_t)r * 256 + c] = res;
    else if (r < 262) M2[(size_t)(r - 256) * 256 + c] = res;
    else cc[c] = res;
}

__global__ void k_pre_emb(const float* __restrict__ emb,
                          const float* __restrict__ W_ai, const float* __restrict__ b_ai,
                          const float* __restrict__ W_aj, const float* __restrict__ b_aj,
                          float* __restrict__ Ai, float* __restrict__ Aj)
{
    const int r = blockIdx.x, c = threadIdx.x;     // grid 200
    const int zz = r % 100, side = r / 100;
    float res = dot256(emb + (size_t)zz * 256, side ? W_aj : W_ai, c)
              + (side ? b_aj[c] : b_ai[c]);
    (side ? Aj : Ai)[(size_t)zz * 256 + c] = res;
}

__global__ void k_pre_m0(const float* __restrict__ W_dist, const float* __restrict__ b_dist,
                         const float* __restrict__ M1, float* __restrict__ M0, float* __restrict__ c0)
{
    const int r = blockIdx.x, c = threadIdx.x;     // grid 51
    const float* a = (r < 50) ? (W_dist + (size_t)r * 256) : b_dist;
    float res = dot256(a, M1, c);
    if (r < 50) M0[(size_t)r * 256 + c] = res; else c0[c] = res;
}

__global__ void k_pre_g(const float* __restrict__ Ai, const float* __restrict__ Aj,
                        const float* __restrict__ Wg1, const float* __restrict__ Wg2,
                        float* __restrict__ Gi, float* __restrict__ Gj)
{
    const int r = blockIdx.x, c = threadIdx.x;     // grid 200
    const int zz = r % 100, side = r / 100;
    float res = side ? dot256(Aj + (size_t)zz * 256, Wg2, c)
                     : dot256(Ai + (size_t)zz * 256, Wg1, c);
    (side ? Gj : Gi)[(size_t)zz * 256 + c] = res;
}

__global__ void k_htable(const float* __restrict__ Gi, const float* __restrict__ Gj,
                         const float* __restrict__ Wexp,
                         float* __restrict__ Hi, bf16* __restrict__ Hjb)
{
    const int zg = blockIdx.x;                     // grid 1000
    const int zz = zg / 10, g = zg - zz * 10;
    const int f = threadIdx.x;                     // 128
    const float* w  = Wexp + (size_t)g * 32768 + f;
    const float* gi = Gi + (size_t)zz * 256;
    const float* gj = Gj + (size_t)zz * 256;
    float a0=0,a1=0,a2=0,a3=0,b0=0,b1=0,b2=0,b3=0;
    for (int k = 0; k < 256; k += 4) {
        const float w0 = w[k*128], w1 = w[(k+1)*128], w2 = w[(k+2)*128], w3 = w[(k+3)*128];
        a0 += gi[k]*w0;   a1 += gi[k+1]*w1; a2 += gi[k+2]*w2; a3 += gi[k+3]*w3;
        b0 += gj[k]*w0;   b1 += gj[k+1]*w1; b2 += gj[k+2]*w2; b3 += gj[k+3]*w3;
    }
    Hi[(size_t)zg * 128 + f] = (a0+a1)+(a2+a3);
    Hjb[(size_t)zz * 2048 + (g >> 3) * 1024 + f * 8 + (g & 7)] = (bf16)((b0+b1)+(b2+b3));
}

// PTc[ck][kh][f][8] bf16: element = PT[k=ck*16+kh*8+j][f]
__global__ void k_ptc(const float* __restrict__ M0, const float* __restrict__ M2,
                      const float* __restrict__ c0, const float* __restrict__ cc,
                      const float* __restrict__ Wexp, const float* __restrict__ b_exp,
                      bf16* __restrict__ PTc)
{
    const int b = blockIdx.x;                      // grid 592 = 37*16
    const int ck = b >> 4, kl = b & 15;
    const int f = threadIdx.x;                     // 128
    const int k = ck * 16 + kl;
    float val = 0.f;
    if (k < 580) {
        const float* arow; int g; float bias = 0.f;
        if (k < 500)      { g = k / 50; arow = M0 + (size_t)(k - g * 50) * 256; }
        else if (k < 560) { const int jj = k - 500; g = jj / 6; arow = M2 + (size_t)(jj - g * 6) * 256; }
        else if (k < 570) { g = k - 560; arow = c0; }
        else              { g = k - 570; arow = cc; bias = b_exp[g * 128 + f]; }
        const float* w = Wexp + (size_t)g * 32768 + f;
        float s0=0,s1=0,s2=0,s3=0;
        for (int c2 = 0; c2 < 256; c2 += 4) {
            s0 += arow[c2]   * w[(c2)   * 128];
            s1 += arow[c2+1] * w[(c2+1) * 128];
            s2 += arow[c2+2] * w[(c2+2) * 128];
            s3 += arow[c2+3] * w[(c2+3) * 128];
        }
        val = (s0+s1)+(s2+s3) + bias;
    }
    PTc[(size_t)ck * 2048 + (kl >> 3) * 1024 + f * 8 + (kl & 7)] = (bf16)val;
}

// ---------------- fused histograms (src cnt + z(dst) bins) ----------------

__global__ void k_hists(const int* __restrict__ esrc, const int* __restrict__ edst,
                        const int* __restrict__ z,
                        int* __restrict__ cnt, int* __restrict__ zbins)
{
    __shared__ int h[NZ];
    for (int i = threadIdx.x; i < NZ; i += 256) h[i] = 0;
    __syncthreads();
    const int e = blockIdx.x * 256 + threadIdx.x;
    if (e < NEDGES) {
        atomicAdd(&cnt[esrc[e]], 1);            // 50K addresses: low contention
        atomicAdd(&h[z[edst[e]]], 1);           // LDS
    }
    __syncthreads();
    for (int i = threadIdx.x; i < NZ; i += 256) if (h[i]) atomicAdd(&zbins[i], h[i]);
}

__global__ void k_zscan(const int* __restrict__ zbins, int* __restrict__ zcursor,
                        int* __restrict__ blk2z)
{
    __shared__ int st[NZ + 1];
    if (threadIdx.x == 0) {
        int s = 0;
        for (int zz = 0; zz < NZ; ++zz) {
            st[zz] = s; zcursor[zz] = s;
            s += ((zbins[zz] + 63) >> 6) << 6;
        }
        st[NZ] = s;
    }
    __syncthreads();
    for (int b = threadIdx.x; b < NBLK; b += 256) blk2z[b] = 0;
    __syncthreads();
    if (threadIdx.x < NZ) {
        const int zz = threadIdx.x;
        for (int b = st[zz] >> 6; b < (st[zz + 1] >> 6); ++b) blk2z[b] = zz;
    }
}

__global__ void k_scan(const int* __restrict__ cnt, int* __restrict__ startp,
                       int* __restrict__ cursor, int n)
{
    __shared__ int part[1024];
    const int tid = threadIdx.x;
    const int chunk = (n + 1023) >> 10;
    const int lo = tid * chunk;
    const int hi = min(lo + chunk, n);
    int s = 0;
    for (int i = lo; i < hi; ++i) s += cnt[i];
    part[tid] = s;
    __syncthreads();
    for (int off = 1; off < 1024; off <<= 1) {
        int t = part[tid];
        if (tid >= off) t += part[tid - off];
        __syncthreads();
        part[tid] = t;
        __syncthreads();
    }
    int run = (tid == 0) ? 0 : part[tid - 1];
    for (int i = lo; i < hi; ++i) { startp[i] = run; cursor[i] = run; run += cnt[i]; }
}

// ---------------- privatized bucket fill (z-sort scatter + src CSR fill) ----
// 1024 edges/block. LDS-histogram rank + one global atomicAdd per (block,bin).
#define ZF_EPB 1024
__global__ void __launch_bounds__(256) k_zfill(
    const int* __restrict__ edst, const int* __restrict__ z,
    const int* __restrict__ esrc,
    int* __restrict__ zcursor, int* __restrict__ cursor,
    int* __restrict__ perm, int* __restrict__ csr)
{
    __shared__ int h[NZ];
    __shared__ int base[NZ];
    const int t = threadIdx.x;
    for (int i = t; i < NZ; i += 256) h[i] = 0;
    __syncthreads();
    const int e0 = blockIdx.x * ZF_EPB;
    int rank[4], zb[4];
#pragma unroll
    for (int k2 = 0; k2 < 4; ++k2) {
        const int e = e0 + t + k2 * 256;
        if (e < NEDGES) { zb[k2] = z[edst[e]]; rank[k2] = atomicAdd(&h[zb[k2]], 1); }
        else zb[k2] = -1;
    }
    __syncthreads();
    for (int i = t; i < NZ; i += 256) base[i] = h[i] ? atomicAdd(&zcursor[i], h[i]) : 0;
    __syncthreads();
#pragma unroll
    for (int k2 = 0; k2 < 4; ++k2) {
        if (zb[k2] >= 0) {
            const int e = e0 + t + k2 * 256;
            const int pos = base[zb[k2]] + rank[k2];
            perm[pos] = e;
            const int p2 = atomicAdd(&cursor[esrc[e]], 1);
            csr[p2] = pos;                      // store PERMUTED id
        }
    }
}

// ---------------- MFMA edge kernel (no LDS, no barriers) ----------------

__device__ __forceinline__ float coeff_one(int k, float d, const float* gate,
                                           const float* Cg, const float* sv)
{
    if (k < 500) {
        const int g = k / 50;
        const float t = d - (float)(k - g * 50) * DELTA_F;
        return Cg[g] * EXP2F(C2T * t * t);
    } else if (k < 560) {
        const int jj = k - 500;
        return gate[jj / 6] * sv[jj - (jj / 6) * 6];
    } else if (k < 570) {
        return Cg[k - 560];
    } else if (k < 580) {
        return gate[k - 570];
    }
    return 0.0f;
}

__global__ void __launch_bounds__(128) k_edge(
    const float* __restrict__ edge_vec,
    const int* __restrict__ perm, const int* __restrict__ blk2z,
    const float* __restrict__ tpar,
    const bf16* __restrict__ PTc, const bf16* __restrict__ Hjb,
    float* __restrict__ gates_ws, float* __restrict__ evb, bf16* __restrict__ eo)
{
    const int tid  = threadIdx.x;
    const int wid  = tid >> 6;
    const int lane = tid & 63;
    const int er   = lane & 31;
    const int kh   = lane >> 5;
    const bool khb = (kh != 0);
    const int pid  = blockIdx.x * BE + wid * 32 + er;
    const int eid  = perm[pid];
    const int zb   = blk2z[blockIdx.x];

    float gate[NG], Cg[NG], sv[6];
    float d = 1.0f, C = 0.0f, vx = 0.f, vy = 0.f, vz = 0.f;
    if (eid >= 0) {
        vx = edge_vec[eid * 3]; vy = edge_vec[eid * 3 + 1]; vz = edge_vec[eid * 3 + 2];
        d = sqrtf(vx * vx + vy * vy + vz * vz);
        C = (d < 5.0f) ? 0.5f * (__cosf(d * 0.6283185307179586f) + 1.0f) : 0.0f;
        float m = -3.0e38f;
#pragma unroll
        for (int g = 0; g < NG; ++g) {
            float r = 1.0f / fmaxf(fabsf(d - tpar[g]), 1e-8f);
            gate[g] = r; m = fmaxf(m, r);
        }
        float ss = 0.f;
#pragma unroll
        for (int g = 0; g < NG; ++g) { float ex = __expf(gate[g] - m); gate[g] = ex; ss += ex; }
        const float inv = 1.0f / ss;
#pragma unroll
        for (int g = 0; g < NG; ++g) gate[g] *= inv;
        const float d2 = d * d;
        sv[0] = d2; sv[1] = d2 * d; sv[2] = d2 * d2;
        sv[3] = sqrtf(d); sv[4] = __logf(d); sv[5] = d;
    } else {
#pragma unroll
        for (int g = 0; g < NG; ++g) gate[g] = 0.f;
#pragma unroll
        for (int m = 0; m < 6; ++m) sv[m] = 0.f;
    }
#pragma unroll
    for (int g = 0; g < NG; ++g) Cg[g] = C * gate[g];

    if (kh == 0 && eid >= 0) {
        float* gw = gates_ws + (size_t)pid * 12;
#pragma unroll
        for (int g = 0; g < NG; ++g) gw[g] = gate[g];
        const float invd = 1.0f / d;
        evb[(size_t)pid * 3 + 0] = vx * invd;
        evb[(size_t)pid * 3 + 1] = vy * invd;
        evb[(size_t)pid * 3 + 2] = vz * invd;
    }

    const float dsh = d - (khb ? 8.0f * DELTA_F : 0.0f);
    const int lanoff = kh * 1024 + er * 8;
    const bf16* __restrict__ Bpt = PTc + lanoff;
    const bf16* __restrict__ Bhj = Hjb + (size_t)zb * 2048 + lanoff;

    f32x16 acc0 = {}, acc1 = {}, acc2 = {}, acc3 = {};

#pragma unroll
    for (int ks = 0; ks < KSTEPS; ++ks) {
        bf16x8 av;
        if (ks < 31) {
#pragma unroll
            for (int j = 0; j < 8; ++j) {
                const int kA = ks * 16 + j;
                const int gA = kA / 50, gB = (kA + 8) / 50;
                const float t = dsh - (float)kA * DELTA_F;
                const float e = EXP2F(C2T * t * t);
                const float mm = (gA == gB) ? Cg[gA] : (khb ? Cg[gB] : Cg[gA]);
                av[j] = (bf16)(mm * e);
            }
        } else if (ks < 37) {
#pragma unroll
            for (int j = 0; j < 8; ++j) {
                const int kA = ks * 16 + j;
                const float va = coeff_one(kA, d, gate, Cg, sv);
                const float vb = coeff_one(kA + 8, d, gate, Cg, sv);
                av[j] = (bf16)(khb ? vb : va);
            }
        } else {
#pragma unroll
            for (int j = 0; j < 8; ++j) {
                const float va = gate[j];
                const float vb = (j < 2) ? gate[8 + j] : 0.0f;
                av[j] = (bf16)(khb ? vb : va);
            }
        }
        const bf16* bp = (ks < 37) ? (Bpt + ks * 2048) : Bhj;
        const bf16x8 b0 = *(const bf16x8*)(bp);
        const bf16x8 b1 = *(const bf16x8*)(bp + 256);
        const bf16x8 b2 = *(const bf16x8*)(bp + 512);
        const bf16x8 b3 = *(const bf16x8*)(bp + 768);
        acc0 = __builtin_amdgcn_mfma_f32_32x32x16_bf16(av, b0, acc0, 0, 0, 0);
        acc1 = __builtin_amdgcn_mfma_f32_32x32x16_bf16(av, b1, acc1, 0, 0, 0);
        acc2 = __builtin_amdgcn_mfma_f32_32x32x16_bf16(av, b2, acc2, 0, 0, 0);
        acc3 = __builtin_amdgcn_mfma_f32_32x32x16_bf16(av, b3, acc3, 0, 0, 0);
    }

    bf16* eor = eo + ((size_t)(blockIdx.x * BE + wid * 32) * 128) + er;
#pragma unroll
    for (int r = 0; r < 16; ++r) {
        const int crow = (r & 3) + 8 * (r >> 2) + 4 * kh;
        bf16* p = eor + (size_t)crow * 128;
        p[0]  = (bf16)acc0[r];
        p[32] = (bf16)acc1[r];
        p[64] = (bf16)acc2[r];
        p[96] = (bf16)acc3[r];
    }
}

// ---------------- gather (+ exact Hi fold) ----------------

__global__ void __launch_bounds__(256) k_gather(
    const bf16* __restrict__ eo, const float* __restrict__ evb,
    const float* __restrict__ gates_ws,
    const int* __restrict__ startp, const int* __restrict__ cnt,
    const int* __restrict__ csr, const int* __restrict__ zarr,
    const float* __restrict__ Hi, float* __restrict__ out)
{
    const int atom = blockIdx.x * 4 + (threadIdx.x >> 6);
    const int lane = threadIdx.x & 63;
    if (atom >= NATOMS) return;
    const int s = startp[atom], len = cnt[atom];
    float a0 = 0, a1 = 0, v00 = 0, v01 = 0, v10 = 0, v11 = 0, v20 = 0, v21 = 0;
    float gs[NG] = {}, e0g[NG] = {}, e1g[NG] = {}, e2g[NG] = {};
    for (int i = 0; i < len; ++i) {
        const int pid = csr[s + i];
        const float evx = evb[(size_t)pid * 3];
        const float evy = evb[(size_t)pid * 3 + 1];
        const float evz = evb[(size_t)pid * 3 + 2];
        const float4* gp = (const float4*)(gates_ws + (size_t)pid * 12);
        const float4 q0 = gp[0], q1 = gp[1], q2 = gp[2];
        const float ga[NG] = {q0.x, q0.y, q0.z, q0.w, q1.x, q1.y, q1.z, q1.w, q2.x, q2.y};
#pragma unroll
        for (int g = 0; g < NG; ++g) {
            gs[g] += ga[g]; e0g[g] += evx * ga[g]; e1g[g] += evy * ga[g]; e2g[g] += evz * ga[g];
        }
        const float y0 = (float)eo[(size_t)pid * 128 + lane];
        const float y1 = (float)eo[(size_t)pid * 128 + 64 + lane];
        a0 += y0; a1 += y1;
        v00 += evx * y0; v01 += evx * y1;
        v10 += evy * y0; v11 += evy * y1;
        v20 += evz * y0; v21 += evz * y1;
    }
    const float* Hrow = Hi + (size_t)zarr[atom] * 1280;
#pragma unroll
    for (int g = 0; g < NG; ++g) {
        const float h0 = Hrow[g * 128 + lane], h1 = Hrow[g * 128 + 64 + lane];
        a0  += gs[g] * h0;  a1  += gs[g] * h1;
        v00 += e0g[g] * h0; v01 += e0g[g] * h1;
        v10 += e1g[g] * h0; v11 += e1g[g] * h1;
        v20 += e2g[g] * h0; v21 += e2g[g] * h1;
    }
    float* ao = out + (size_t)atom * 128;
    ao[lane] = a0; ao[64 + lane] = a1;
    float* vp = out + OUT_VEC + (size_t)atom * 384;
    vp[lane] = v00;        vp[64 + lane] = v01;
    vp[128 + lane] = v10;  vp[192 + lane] = v11;
    vp[256 + lane] = v20;  vp[320 + lane] = v21;
}

__global__ void k_tail(const int* __restrict__ z, const float* __restrict__ pos,
                       const int* __restrict__ batch, float* __restrict__ out)
{
    const int i = blockIdx.x * 256 + threadIdx.x;
    if (i < NATOMS) {
        out[OUT_Z + i] = (float)z[i];
        out[OUT_BATCH + i] = (float)batch[i];
    }
    if (i < 3 * NATOMS) out[OUT_POS + i] = pos[i];
}

// ---------------- launch ----------------

extern "C" void kernel_launch(void* const* d_in, const int* in_sizes, int n_in,
                              void* d_out, int out_size, void* d_ws, size_t ws_size,
                              hipStream_t stream)
{
    const int*   z        = (const int*)d_in[0];
    const float* pos      = (const float*)d_in[1];
    const int*   batch    = (const int*)d_in[2];
    const int*   esrc     = (const int*)d_in[3];
    const int*   edst     = esrc + NEDGES;
    const float* edge_vec = (const float*)d_in[4];
    const float* emb      = (const float*)d_in[5];
    const float* W_dist   = (const float*)d_in[6];
    const float* b_dist   = (const float*)d_in[7];
    const float* W_dt     = (const float*)d_in[8];
    const float* b_dt     = (const float*)d_in[9];
    const float* W_ai     = (const float*)d_in[10];
    const float* b_ai     = (const float*)d_in[11];
    const float* W_aj     = (const float*)d_in[12];
    const float* b_aj     = (const float*)d_in[13];
    const float* W_gamma  = (const float*)d_in[14];
    const float* b_gamma  = (const float*)d_in[15];
    const float* W_exp    = (const float*)d_in[16];
    const float* b_exp    = (const float*)d_in[17];
    const float* tpar     = (const float*)d_in[18];

    float* out = (float*)d_out;
    float* W   = (float*)d_ws;

    const float* Wg1 = W_gamma;
    const float* Wg2 = W_gamma + 256 * 256;
    const float* Wg3 = W_gamma + 512 * 256;

    float* M1 = W + WS_M1;
    float* M0 = W + WS_M0;
    float* c0 = W + WS_C0;
    float* M2 = W + WS_M2;
    float* cc = W + WS_CC;
    float* Ai = W + WS_AI;
    float* Aj = W + WS_AJ;
    float* Gi = W + WS_GI;
    float* Gj = W + WS_GJ;
    float* Hi = W + WS_HI;
    bf16*  Hjb = (bf16*)(W + WS_HJB);
    bf16*  PTc = (bf16*)(W + WS_PTC);
    float* gates = W + WS_GT;
    float* evb   = W + WS_EV;
    bf16*  eo    = (bf16*)(W + WS_EO);
    int*   I     = (int*)(W + WS_I);
    int* cnt    = I + I_CNT;
    int* startp = I + I_START;
    int* cursor = I + I_CUR;
    int* csr    = I + I_CSR;
    int* zbins  = I + I_ZB;
    int* zcur   = I + I_ZC;
    int* b2z    = I + I_B2Z;
    int* perm   = I + I_PERM;

    // precompute chain
    k_pre_dt<<<263, 256, 0, stream>>>(W_dt, b_dt, b_gamma, Wg3, M1, M2, cc);
    k_pre_emb<<<200, 256, 0, stream>>>(emb, W_ai, b_ai, W_aj, b_aj, Ai, Aj);
    k_pre_m0<<<51, 256, 0, stream>>>(W_dist, b_dist, M1, M0, c0);
    k_pre_g<<<200, 256, 0, stream>>>(Ai, Aj, Wg1, Wg2, Gi, Gj);
    hipMemsetAsync(Hjb, 0, 100 * 2048 * sizeof(bf16), stream);
    k_htable<<<1000, 128, 0, stream>>>(Gi, Gj, W_exp, Hi, Hjb);
    k_ptc<<<592, 128, 0, stream>>>(M0, M2, c0, cc, W_exp, b_exp, PTc);

    hipMemsetAsync(cnt, 0, NATOMS * sizeof(int), stream);
    hipMemsetAsync(zbins, 0, 128 * sizeof(int), stream);
    hipMemsetAsync(perm, 0xFF, NBLK * 64 * sizeof(int), stream);

    k_hists<<<(NEDGES + 255) / 256, 256, 0, stream>>>(esrc, edst, z, cnt, zbins);
    k_zscan<<<1, 256, 0, stream>>>(zbins, zcur, b2z);
    k_scan<<<1, 1024, 0, stream>>>(cnt, startp, cursor, NATOMS);
    k_zfill<<<(NEDGES + ZF_EPB - 1) / ZF_EPB, 256, 0, stream>>>(edst, z, esrc, zcur, cursor, perm, csr);

    k_edge<<<NBLK, 128, 0, stream>>>(edge_vec, perm, b2z, tpar, PTc, Hjb, gates, evb, eo);
    k_gather<<<(NATOMS + 3) / 4, 256, 0, stream>>>(eo, evb, gates, startp, cnt, csr, z, Hi, out);
    k_tail<<<(3 * NATOMS + 255) / 256, 256, 0, stream>>>(z, pos, batch, out);
}

// Round 5
// 610.182 us; speedup vs baseline: 4.2592x; 1.1046x over previous
//
#include <hip/hip_runtime.h>
#include <math.h>

typedef __bf16 bf16;
typedef __bf16 bf16x8 __attribute__((ext_vector_type(8)));
typedef float  f32x16 __attribute__((ext_vector_type(16)));

#define NATOMS 50000
#define NEDGES 400000
#define NG 10
#define NZ 100
#define BE 128                 /* edges per k_edge block (4 waves x 32) */
#define NBLK 3225              /* >= ceil((400000 + 100*127)/128) */
#define DELTA_F 0.10204081632653061f          /* 5/49 */

// ---- d_out layout (float elements) ----
#define OUT_VEC   6400000LL
#define OUT_Z     25600000LL
#define OUT_POS   25650000LL
#define OUT_BATCH 25800000LL

// ---- workspace layout (float units) ----
#define WS_M1   0LL
#define WS_M0   65536LL
#define WS_C0   78336LL
#define WS_M2   78592LL
#define WS_CC   80128LL
#define WS_AI   80384LL
#define WS_AJ   105984LL
#define WS_GI   131584LL
#define WS_GJ   157184LL
#define WS_HI   182784LL          /* 100*10*128 f32 */
#define WS_HJB  310784LL          /* 100*2048 bf16 = 102400 fu */
#define WS_PTC  413184LL          /* 37*2048 bf16 = 37888 fu */
#define WS_GT   451072LL          /* [412800][12] f32 */
#define WS_EV   5404672LL         /* [412800][3] f32 */
#define WS_EO   6643072LL         /* [412800][128] bf16 */
#define WS_I    33062272LL        /* int region */
// int region offsets (ints)
#define I_CNT   0
#define I_START 50000
#define I_CUR   100000
#define I_CSR   150000
#define I_ZB    550000
#define I_ZC    550128
#define I_B2Z   550256            /* 3232 ints */
#define I_PERM  553488            /* NBLK*128 = 412800 ints */

// ---------------- helpers ----------------

__device__ __forceinline__ float dot256(const float* __restrict__ a,
                                        const float* __restrict__ B, int c)
{
    float s0 = 0, s1 = 0, s2 = 0, s3 = 0;
    for (int k = 0; k < 256; k += 4) {
        s0 += a[k]     * B[(k)     * 256 + c];
        s1 += a[k + 1] * B[(k + 1) * 256 + c];
        s2 += a[k + 2] * B[(k + 2) * 256 + c];
        s3 += a[k + 3] * B[(k + 3) * 256 + c];
    }
    return (s0 + s1) + (s2 + s3);
}

__device__ __forceinline__ unsigned pack2bf(float a, float b)
{
    union { __bf16 h; unsigned short u; } ca, cb;
    ca.h = (__bf16)a; cb.h = (__bf16)b;
    return (unsigned)ca.u | ((unsigned)cb.u << 16);
}

// ---------------- fused precompute A: dt/emb GEMVs + histograms + tail ------

__global__ void kA(const float* __restrict__ W_dt, const float* __restrict__ b_dt,
                   const float* __restrict__ b_gamma, const float* __restrict__ Wg3,
                   float* __restrict__ M1, float* __restrict__ M2, float* __restrict__ cc,
                   const float* __restrict__ emb,
                   const float* __restrict__ W_ai, const float* __restrict__ b_ai,
                   const float* __restrict__ W_aj, const float* __restrict__ b_aj,
                   float* __restrict__ Ai, float* __restrict__ Aj,
                   const int* __restrict__ esrc, const int* __restrict__ edst,
                   const int* __restrict__ z,
                   int* __restrict__ cnt, int* __restrict__ zbins,
                   const float* __restrict__ pos, const int* __restrict__ batch,
                   float* __restrict__ out)
{
    const int r = blockIdx.x, tid = threadIdx.x;
    if (r < 263) {
        const float* a = (r < 262) ? (W_dt + (size_t)r * 256) : b_dt;
        float res = dot256(a, Wg3, tid);
        if (r == 262) res += b_gamma[tid];
        if (r < 256) M1[(size_t)r * 256 + tid] = res;
        else if (r < 262) M2[(size_t)(r - 256) * 256 + tid] = res;
        else cc[tid] = res;
    } else if (r < 463) {
        const int r2 = r - 263;
        const int zz = r2 % 100, side = r2 / 100;
        float res = dot256(emb + (size_t)zz * 256, side ? W_aj : W_ai, tid)
                  + (side ? b_aj[tid] : b_ai[tid]);
        (side ? Aj : Ai)[(size_t)zz * 256 + tid] = res;
    } else if (r < 2026) {
        __shared__ int h[NZ];
        for (int i = tid; i < NZ; i += 256) h[i] = 0;
        __syncthreads();
        const int e = (r - 463) * 256 + tid;
        if (e < NEDGES) {
            atomicAdd(&cnt[esrc[e]], 1);
            atomicAdd(&h[z[edst[e]]], 1);
        }
        __syncthreads();
        for (int i = tid; i < NZ; i += 256) if (h[i]) atomicAdd(&zbins[i], h[i]);
    } else {
        const int i = (r - 2026) * 256 + tid;
        if (i < NATOMS) {
            out[OUT_Z + i] = (float)z[i];
            out[OUT_BATCH + i] = (float)batch[i];
        }
        if (i < 3 * NATOMS) out[OUT_POS + i] = pos[i];
    }
}

// ---------------- fused precompute B: M0/c0 + Gi/Gj ----------------

__global__ void kB(const float* __restrict__ W_dist, const float* __restrict__ b_dist,
                   const float* __restrict__ M1, float* __restrict__ M0, float* __restrict__ c0,
                   const float* __restrict__ Ai, const float* __restrict__ Aj,
                   const float* __restrict__ Wg1, const float* __restrict__ Wg2,
                   float* __restrict__ Gi, float* __restrict__ Gj)
{
    const int r = blockIdx.x, c = threadIdx.x;
    if (r < 51) {
        const float* a = (r < 50) ? (W_dist + (size_t)r * 256) : b_dist;
        float res = dot256(a, M1, c);
        if (r < 50) M0[(size_t)r * 256 + c] = res; else c0[c] = res;
    } else {
        const int r2 = r - 51;
        const int zz = r2 % 100, side = r2 / 100;
        float res = side ? dot256(Aj + (size_t)zz * 256, Wg2, c)
                         : dot256(Ai + (size_t)zz * 256, Wg1, c);
        (side ? Gj : Gi)[(size_t)zz * 256 + c] = res;
    }
}

// ---------------- fused precompute C: H tables + PTc ----------------

__global__ void kC(const float* __restrict__ Gi, const float* __restrict__ Gj,
                   const float* __restrict__ Wexp,
                   float* __restrict__ Hi, bf16* __restrict__ Hjb,
                   const float* __restrict__ M0, const float* __restrict__ M2,
                   const float* __restrict__ c0, const float* __restrict__ cc,
                   const float* __restrict__ b_exp, bf16* __restrict__ PTc)
{
    const int r = blockIdx.x;
    const int f = threadIdx.x;            // 128
    if (r < 1000) {
        const int zz = r / 10, g = r - zz * 10;
        const float* w  = Wexp + (size_t)g * 32768 + f;
        const float* gi = Gi + (size_t)zz * 256;
        const float* gj = Gj + (size_t)zz * 256;
        float a0=0,a1=0,a2=0,a3=0,b0=0,b1=0,b2=0,b3=0;
        for (int k = 0; k < 256; k += 4) {
            const float w0 = w[k*128], w1 = w[(k+1)*128], w2 = w[(k+2)*128], w3 = w[(k+3)*128];
            a0 += gi[k]*w0;   a1 += gi[k+1]*w1; a2 += gi[k+2]*w2; a3 += gi[k+3]*w3;
            b0 += gj[k]*w0;   b1 += gj[k+1]*w1; b2 += gj[k+2]*w2; b3 += gj[k+3]*w3;
        }
        Hi[(size_t)r * 128 + f] = (a0+a1)+(a2+a3);
        Hjb[(size_t)zz * 2048 + (g >> 3) * 1024 + f * 8 + (g & 7)] = (bf16)((b0+b1)+(b2+b3));
    } else {
        const int b = r - 1000;           // 0..591
        const int ck = b >> 4, kl = b & 15;
        const int k = ck * 16 + kl;
        float val = 0.f;
        if (k < 580) {
            const float* arow; int g; float bias = 0.f;
            if (k < 500)      { g = k / 50; arow = M0 + (size_t)(k - g * 50) * 256; }
            else if (k < 560) { const int jj = k - 500; g = jj / 6; arow = M2 + (size_t)(jj - g * 6) * 256; }
            else if (k < 570) { g = k - 560; arow = c0; }
            else              { g = k - 570; arow = cc; bias = b_exp[g * 128 + f]; }
            const float* w = Wexp + (size_t)g * 32768 + f;
            float s0=0,s1=0,s2=0,s3=0;
            for (int c2 = 0; c2 < 256; c2 += 4) {
                s0 += arow[c2]   * w[(c2)   * 128];
                s1 += arow[c2+1] * w[(c2+1) * 128];
                s2 += arow[c2+2] * w[(c2+2) * 128];
                s3 += arow[c2+3] * w[(c2+3) * 128];
            }
            val = (s0+s1)+(s2+s3) + bias;
        }
        PTc[(size_t)ck * 2048 + (kl >> 3) * 1024 + f * 8 + (kl & 7)] = (bf16)val;
    }
}

// ---------------- fused scans (block0: src CSR scan, block1: z scan) --------

__global__ void kD(const int* __restrict__ cnt, int* __restrict__ startp,
                   int* __restrict__ cursor,
                   const int* __restrict__ zbins, int* __restrict__ zcursor,
                   int* __restrict__ blk2z)
{
    const int tid = threadIdx.x;
    if (blockIdx.x == 0) {
        __shared__ int part[1024];
        const int chunk = (NATOMS + 1023) >> 10;
        const int lo = tid * chunk;
        const int hi = min(lo + chunk, NATOMS);
        int s = 0;
        for (int i = lo; i < hi; ++i) s += cnt[i];
        part[tid] = s;
        __syncthreads();
        for (int off = 1; off < 1024; off <<= 1) {
            int t = part[tid];
            if (tid >= off) t += part[tid - off];
            __syncthreads();
            part[tid] = t;
            __syncthreads();
        }
        int run = (tid == 0) ? 0 : part[tid - 1];
        for (int i = lo; i < hi; ++i) { startp[i] = run; cursor[i] = run; run += cnt[i]; }
    } else {
        __shared__ int st[NZ + 1];
        if (tid == 0) {
            int s = 0;
            for (int zz = 0; zz < NZ; ++zz) {
                st[zz] = s; zcursor[zz] = s;
                s += ((zbins[zz] + BE - 1) / BE) * BE;    // 128-aligned buckets
            }
            st[NZ] = s;
        }
        __syncthreads();
        for (int b = tid; b < NBLK; b += 1024) blk2z[b] = 0;
        __syncthreads();
        if (tid < NZ) {
            const int zz = tid;
            for (int b = st[zz] / BE; b < st[zz + 1] / BE; ++b) blk2z[b] = zz;
        }
    }
}

// ---------------- privatized bucket fill (z-sort scatter + src CSR fill) ----
#define ZF_EPB 1024
__global__ void __launch_bounds__(256) k_zfill(
    const int* __restrict__ edst, const int* __restrict__ z,
    const int* __restrict__ esrc,
    int* __restrict__ zcursor, int* __restrict__ cursor,
    int* __restrict__ perm, int* __restrict__ csr)
{
    __shared__ int h[NZ];
    __shared__ int base[NZ];
    const int t = threadIdx.x;
    for (int i = t; i < NZ; i += 256) h[i] = 0;
    __syncthreads();
    const int e0 = blockIdx.x * ZF_EPB;
    int rank[4], zb[4];
#pragma unroll
    for (int k2 = 0; k2 < 4; ++k2) {
        const int e = e0 + t + k2 * 256;
        if (e < NEDGES) { zb[k2] = z[edst[e]]; rank[k2] = atomicAdd(&h[zb[k2]], 1); }
        else zb[k2] = -1;
    }
    __syncthreads();
    for (int i = t; i < NZ; i += 256) base[i] = h[i] ? atomicAdd(&zcursor[i], h[i]) : 0;
    __syncthreads();
#pragma unroll
    for (int k2 = 0; k2 < 4; ++k2) {
        if (zb[k2] >= 0) {
            const int e = e0 + t + k2 * 256;
            const int pos = base[zb[k2]] + rank[k2];
            perm[pos] = e;
            const int p2 = atomicAdd(&cursor[esrc[e]], 1);
            csr[p2] = pos;
        }
    }
}

// ---------------- MFMA edge kernel: LDS-shared B, reg G-table ----------------

__device__ __forceinline__ float coeff(int k, const unsigned* Gp, const float* gate,
                                       const float* sv, float C)
{
    if (k < 500) {
        const int g = k / 50, rb = k - g * 50;
        const unsigned w = Gp[rb >> 1];
        const unsigned bits = (rb & 1) ? (w & 0xffff0000u) : (w << 16);
        return gate[g] * __uint_as_float(bits);
    } else if (k < 560) {
        const int jj = k - 500;
        return gate[jj / 6] * sv[jj - (jj / 6) * 6];
    } else if (k < 570) {
        return C * gate[k - 560];
    } else if (k < 580) {
        return gate[k - 570];
    }
    return 0.0f;
}

__global__ void __launch_bounds__(256, 3) k_edge(
    const float* __restrict__ edge_vec,
    const int* __restrict__ perm, const int* __restrict__ blk2z,
    const float* __restrict__ tpar,
    const bf16* __restrict__ PTc, const bf16* __restrict__ Hjb,
    float* __restrict__ gates_ws, float* __restrict__ evb, bf16* __restrict__ eo)
{
    __shared__ __align__(16) bf16 Bst[2][2048];
    __shared__ __align__(16) bf16 Bhj[2048];

    const int t    = threadIdx.x;
    const int wid  = t >> 6;
    const int lane = t & 63;
    const int er   = lane & 31;
    const int kh   = lane >> 5;
    const bool khb = (kh != 0);
    const int base = blockIdx.x * BE;
    const int pid  = base + wid * 32 + er;

    if (perm[base] < 0) return;                 // all-dummy block (uniform)

    const int zb  = blk2z[blockIdx.x];
    const int eid = perm[pid];

    // ---- per-edge scalars ----
    float gate[NG], sv[6];
    float d = 1.0f, C = 0.0f, vx = 0.f, vy = 0.f, vz = 0.f;
    if (eid >= 0) {
        vx = edge_vec[eid * 3]; vy = edge_vec[eid * 3 + 1]; vz = edge_vec[eid * 3 + 2];
        d = sqrtf(vx * vx + vy * vy + vz * vz);
        C = (d < 5.0f) ? 0.5f * (__cosf(d * 0.6283185307179586f) + 1.0f) : 0.0f;
        float m = -3.0e38f;
#pragma unroll
        for (int g = 0; g < NG; ++g) {
            float r = 1.0f / fmaxf(fabsf(d - tpar[g]), 1e-8f);
            gate[g] = r; m = fmaxf(m, r);
        }
        float ss = 0.f;
#pragma unroll
        for (int g = 0; g < NG; ++g) { float ex = __expf(gate[g] - m); gate[g] = ex; ss += ex; }
        const float inv = 1.0f / ss;
#pragma unroll
        for (int g = 0; g < NG; ++g) gate[g] *= inv;
        const float d2 = d * d;
        sv[0] = d2; sv[1] = d2 * d; sv[2] = d2 * d2;
        sv[3] = sqrtf(d); sv[4] = __logf(d); sv[5] = d;
    } else {
#pragma unroll
        for (int g = 0; g < NG; ++g) gate[g] = 0.f;
#pragma unroll
        for (int m2 = 0; m2 < 6; ++m2) sv[m2] = 0.f;
    }

    // ---- packed Gaussian table (bf16 pairs, C folded in): 25 VGPRs ----
    unsigned Gp[25];
#pragma unroll
    for (int p = 0; p < 25; ++p) {
        const float t0 = d - (float)(2 * p) * DELTA_F;
        const float t1 = t0 - DELTA_F;
        const float g0 = C * __expf(-48.02f * t0 * t0);
        const float g1 = C * __expf(-48.02f * t1 * t1);
        Gp[p] = pack2bf(g0, g1);
    }

    if (kh == 0 && eid >= 0) {
        float* gw = gates_ws + (size_t)pid * 12;
#pragma unroll
        for (int g = 0; g < NG; ++g) gw[g] = gate[g];
        const float invd = 1.0f / d;
        evb[(size_t)pid * 3 + 0] = vx * invd;
        evb[(size_t)pid * 3 + 1] = vy * invd;
        evb[(size_t)pid * 3 + 2] = vz * invd;
    }

    // ---- stage prologue: Hj + chunk0 into LDS, chunk1 into regs ----
    const float4* PTc4 = (const float4*)PTc;
    const float4* Hj4  = (const float4*)(Hjb + (size_t)zb * 2048);
    float4 h4 = Hj4[t];
    float4 c4 = PTc4[t];
    *(float4*)&Bhj[t * 8] = h4;
    *(float4*)&Bst[0][t * 8] = c4;
    float4 st = PTc4[256 + t];
    __syncthreads();

    f32x16 acc0 = {}, acc1 = {}, acc2 = {}, acc3 = {};
    const int lanoff = kh * 1024 + er * 8;

#define MFMA4(AV, BP) do { \
        const bf16x8 b0 = *(const bf16x8*)(BP); \
        const bf16x8 b1 = *(const bf16x8*)((BP) + 256); \
        const bf16x8 b2 = *(const bf16x8*)((BP) + 512); \
        const bf16x8 b3 = *(const bf16x8*)((BP) + 768); \
        acc0 = __builtin_amdgcn_mfma_f32_32x32x16_bf16(AV, b0, acc0, 0, 0, 0); \
        acc1 = __builtin_amdgcn_mfma_f32_32x32x16_bf16(AV, b1, acc1, 0, 0, 0); \
        acc2 = __builtin_amdgcn_mfma_f32_32x32x16_bf16(AV, b2, acc2, 0, 0, 0); \
        acc3 = __builtin_amdgcn_mfma_f32_32x32x16_bf16(AV, b3, acc3, 0, 0, 0); \
    } while (0)

    // ---- Hj K-step (gate coefficients) ----
    {
        bf16x8 av;
#pragma unroll
        for (int j = 0; j < 8; ++j) {
            const float va = gate[j];
            const float vb = (j < 2) ? gate[8 + j] : 0.0f;
            av[j] = (bf16)(khb ? vb : va);
        }
        MFMA4(av, &Bhj[lanoff]);
    }

    // ---- main loop over 37 PT chunks, double-buffered ----
#pragma unroll
    for (int ks = 0; ks < 37; ++ks) {
        if (ks + 1 <= 36) *(float4*)&Bst[(ks + 1) & 1][t * 8] = st;
        if (ks + 2 <= 36) st = PTc4[(size_t)(ks + 2) * 256 + t];
        bf16x8 av;
#pragma unroll
        for (int j = 0; j < 8; ++j) {
            const float va = coeff(ks * 16 + j,     Gp, gate, sv, C);
            const float vb = coeff(ks * 16 + 8 + j, Gp, gate, sv, C);
            av[j] = (bf16)(khb ? vb : va);
        }
        MFMA4(av, &Bst[ks & 1][lanoff]);
        __syncthreads();
    }
#undef MFMA4

    // ---- epilogue: block-local rows, coalesced-ish bf16 stores ----
    bf16* eor = eo + (size_t)(base + wid * 32) * 128 + er;
#pragma unroll
    for (int r = 0; r < 16; ++r) {
        const int crow = (r & 3) + 8 * (r >> 2) + 4 * kh;
        bf16* p = eor + (size_t)crow * 128;
        p[0]  = (bf16)acc0[r];
        p[32] = (bf16)acc1[r];
        p[64] = (bf16)acc2[r];
        p[96] = (bf16)acc3[r];
    }
}

// ---------------- gather (+ exact Hi fold), paired-feature layout ----------

__global__ void __launch_bounds__(256) k_gather(
    const bf16* __restrict__ eo, const float* __restrict__ evb,
    const float* __restrict__ gates_ws,
    const int* __restrict__ startp, const int* __restrict__ cnt,
    const int* __restrict__ csr, const int* __restrict__ zarr,
    const float* __restrict__ Hi, float* __restrict__ out)
{
    const int atom = blockIdx.x * 4 + (threadIdx.x >> 6);
    const int lane = threadIdx.x & 63;
    if (atom >= NATOMS) return;
    const int s = startp[atom], len = cnt[atom];
    const unsigned* eo32 = (const unsigned*)eo;
    float a0 = 0, a1 = 0, v00 = 0, v01 = 0, v10 = 0, v11 = 0, v20 = 0, v21 = 0;
    float gs[NG] = {}, e0g[NG] = {}, e1g[NG] = {}, e2g[NG] = {};
    for (int i = 0; i < len; ++i) {
        const int pid = csr[s + i];
        const float evx = evb[(size_t)pid * 3];
        const float evy = evb[(size_t)pid * 3 + 1];
        const float evz = evb[(size_t)pid * 3 + 2];
        const float4* gp = (const float4*)(gates_ws + (size_t)pid * 12);
        const float4 q0 = gp[0], q1 = gp[1], q2 = gp[2];
        const float ga[NG] = {q0.x, q0.y, q0.z, q0.w, q1.x, q1.y, q1.z, q1.w, q2.x, q2.y};
#pragma unroll
        for (int g = 0; g < NG; ++g) {
            gs[g] += ga[g]; e0g[g] += evx * ga[g]; e1g[g] += evy * ga[g]; e2g[g] += evz * ga[g];
        }
        const unsigned u = eo32[(size_t)pid * 64 + lane];
        const float y0 = __uint_as_float(u << 16);
        const float y1 = __uint_as_float(u & 0xffff0000u);
        a0 += y0; a1 += y1;
        v00 += evx * y0; v01 += evx * y1;
        v10 += evy * y0; v11 += evy * y1;
        v20 += evz * y0; v21 += evz * y1;
    }
    const float* Hrow = Hi + (size_t)zarr[atom] * 1280;
#pragma unroll
    for (int g = 0; g < NG; ++g) {
        const float2 h2 = *(const float2*)(Hrow + g * 128 + 2 * lane);
        a0  += gs[g] * h2.x;  a1  += gs[g] * h2.y;
        v00 += e0g[g] * h2.x; v01 += e0g[g] * h2.y;
        v10 += e1g[g] * h2.x; v11 += e1g[g] * h2.y;
        v20 += e2g[g] * h2.x; v21 += e2g[g] * h2.y;
    }
    float* ao = out + (size_t)atom * 128;
    *(float2*)(ao + 2 * lane) = make_float2(a0, a1);
    float* vp = out + OUT_VEC + (size_t)atom * 384;
    *(float2*)(vp + 2 * lane)       = make_float2(v00, v01);
    *(float2*)(vp + 128 + 2 * lane) = make_float2(v10, v11);
    *(float2*)(vp + 256 + 2 * lane) = make_float2(v20, v21);
}

// ---------------- launch ----------------

extern "C" void kernel_launch(void* const* d_in, const int* in_sizes, int n_in,
                              void* d_out, int out_size, void* d_ws, size_t ws_size,
                              hipStream_t stream)
{
    const int*   z        = (const int*)d_in[0];
    const float* pos      = (const float*)d_in[1];
    const int*   batch    = (const int*)d_in[2];
    const int*   esrc     = (const int*)d_in[3];
    const int*   edst     = esrc + NEDGES;
    const float* edge_vec = (const float*)d_in[4];
    const float* emb      = (const float*)d_in[5];
    const float* W_dist   = (const float*)d_in[6];
    const float* b_dist   = (const float*)d_in[7];
    const float* W_dt     = (const float*)d_in[8];
    const float* b_dt     = (const float*)d_in[9];
    const float* W_ai     = (const float*)d_in[10];
    const float* b_ai     = (const float*)d_in[11];
    const float* W_aj     = (const float*)d_in[12];
    const float* b_aj     = (const float*)d_in[13];
    const float* W_gamma  = (const float*)d_in[14];
    const float* b_gamma  = (const float*)d_in[15];
    const float* W_exp    = (const float*)d_in[16];
    const float* b_exp    = (const float*)d_in[17];
    const float* tpar     = (const float*)d_in[18];

    float* out = (float*)d_out;
    float* W   = (float*)d_ws;

    const float* Wg1 = W_gamma;
    const float* Wg2 = W_gamma + 256 * 256;
    const float* Wg3 = W_gamma + 512 * 256;

    float* M1 = W + WS_M1;
    float* M0 = W + WS_M0;
    float* c0 = W + WS_C0;
    float* M2 = W + WS_M2;
    float* cc = W + WS_CC;
    float* Ai = W + WS_AI;
    float* Aj = W + WS_AJ;
    float* Gi = W + WS_GI;
    float* Gj = W + WS_GJ;
    float* Hi = W + WS_HI;
    bf16*  Hjb = (bf16*)(W + WS_HJB);
    bf16*  PTc = (bf16*)(W + WS_PTC);
    float* gates = W + WS_GT;
    float* evb   = W + WS_EV;
    bf16*  eo    = (bf16*)(W + WS_EO);
    int*   I     = (int*)(W + WS_I);
    int* cnt    = I + I_CNT;
    int* startp = I + I_START;
    int* cursor = I + I_CUR;
    int* csr    = I + I_CSR;
    int* zbins  = I + I_ZB;
    int* zcur   = I + I_ZC;
    int* b2z    = I + I_B2Z;
    int* perm   = I + I_PERM;

    hipMemsetAsync(cnt, 0, NATOMS * sizeof(int), stream);
    hipMemsetAsync(zbins, 0, 128 * sizeof(int), stream);
    hipMemsetAsync(perm, 0xFF, (size_t)NBLK * BE * sizeof(int), stream);
    hipMemsetAsync(Hjb, 0, 100 * 2048 * sizeof(bf16), stream);

    kA<<<2613, 256, 0, stream>>>(W_dt, b_dt, b_gamma, Wg3, M1, M2, cc,
                                 emb, W_ai, b_ai, W_aj, b_aj, Ai, Aj,
                                 esrc, edst, z, cnt, zbins, pos, batch, out);
    kB<<<251, 256, 0, stream>>>(W_dist, b_dist, M1, M0, c0, Ai, Aj, Wg1, Wg2, Gi, Gj);
    kC<<<1592, 128, 0, stream>>>(Gi, Gj, W_exp, Hi, Hjb, M0, M2, c0, cc, b_exp, PTc);
    kD<<<2, 1024, 0, stream>>>(cnt, startp, cursor, zbins, zcur, b2z);
    k_zfill<<<(NEDGES + ZF_EPB - 1) / ZF_EPB, 256, 0, stream>>>(edst, z, esrc, zcur, cursor, perm, csr);

    k_edge<<<NBLK, 256, 0, stream>>>(edge_vec, perm, b2z, tpar, PTc, Hjb, gates, evb, eo);
    k_gather<<<(NATOMS + 3) / 4, 256, 0, stream>>>(eo, evb, gates, startp, cnt, csr, z, Hi, out);
}

// Round 6
// 389.759 us; speedup vs baseline: 6.6679x; 1.5655x over previous
//
#include <hip/hip_runtime.h>
#include <math.h>

typedef __bf16 bf16;
typedef __bf16 bf16x8 __attribute__((ext_vector_type(8)));
typedef float  f32x16 __attribute__((ext_vector_type(16)));

#define NATOMS 50000
#define NEDGES 400000
#define NG 10
#define NZ 100
#define BE 128                 /* edges per k_edge block (4 waves x 32) */
#define NBLK 3225              /* >= ceil((400000 + 100*127)/128) */
#define NLDSC 14               /* PT chunks resident in LDS (60 KB with Hj) */
#define DELTA_F 0.10204081632653061f          /* 5/49 */

// ---- d_out layout (float elements) ----
#define OUT_VEC   6400000LL
#define OUT_Z     25600000LL
#define OUT_POS   25650000LL
#define OUT_BATCH 25800000LL

// ---- workspace layout (float units) ----
#define WS_M1   0LL
#define WS_M0   65536LL
#define WS_C0   78336LL
#define WS_M2   78592LL
#define WS_CC   80128LL
#define WS_AI   80384LL
#define WS_AJ   105984LL
#define WS_GI   131584LL
#define WS_GJ   157184LL
#define WS_HI   182784LL          /* 100*10*128 f32 */
#define WS_HJB  310784LL          /* 100*2048 bf16 = 102400 fu */
#define WS_PTC  413184LL          /* 37*2048 bf16 = 37888 fu */
#define WS_GT   451072LL          /* [412800][12] f32 */
#define WS_EV   5404672LL         /* [412800][4] f32 */
#define WS_EO   7055872LL         /* [412800][128] bf16 = 26419200 fu */
#define WS_I    33475072LL        /* int region */
// int region offsets (ints)
#define I_CNT   0
#define I_START 50000
#define I_CUR   100000
#define I_CSR   150000
#define I_ZB    550000
#define I_ZC    550128
#define I_B2Z   550256            /* 3232 ints */
#define I_PERM  553488            /* NBLK*128 = 412800 ints */

// ---------------- helpers ----------------

__device__ __forceinline__ float dot256(const float* __restrict__ a,
                                        const float* __restrict__ B, int c)
{
    float s0 = 0, s1 = 0, s2 = 0, s3 = 0;
    for (int k = 0; k < 256; k += 4) {
        s0 += a[k]     * B[(k)     * 256 + c];
        s1 += a[k + 1] * B[(k + 1) * 256 + c];
        s2 += a[k + 2] * B[(k + 2) * 256 + c];
        s3 += a[k + 3] * B[(k + 3) * 256 + c];
    }
    return (s0 + s1) + (s2 + s3);
}

__device__ __forceinline__ unsigned pack2bf(float a, float b)
{
    union { __bf16 h; unsigned short u; } ca, cb;
    ca.h = (__bf16)a; cb.h = (__bf16)b;
    return (unsigned)ca.u | ((unsigned)cb.u << 16);
}

// ---------------- fused precompute A: dt/emb GEMVs + histograms + tail ------

__global__ void kA(const float* __restrict__ W_dt, const float* __restrict__ b_dt,
                   const float* __restrict__ b_gamma, const float* __restrict__ Wg3,
                   float* __restrict__ M1, float* __restrict__ M2, float* __restrict__ cc,
                   const float* __restrict__ emb,
                   const float* __restrict__ W_ai, const float* __restrict__ b_ai,
                   const float* __restrict__ W_aj, const float* __restrict__ b_aj,
                   float* __restrict__ Ai, float* __restrict__ Aj,
                   const int* __restrict__ esrc, const int* __restrict__ edst,
                   const int* __restrict__ z,
                   int* __restrict__ cnt, int* __restrict__ zbins,
                   const float* __restrict__ pos, const int* __restrict__ batch,
                   float* __restrict__ out)
{
    const int r = blockIdx.x, tid = threadIdx.x;
    if (r < 263) {
        const float* a = (r < 262) ? (W_dt + (size_t)r * 256) : b_dt;
        float res = dot256(a, Wg3, tid);
        if (r == 262) res += b_gamma[tid];
        if (r < 256) M1[(size_t)r * 256 + tid] = res;
        else if (r < 262) M2[(size_t)(r - 256) * 256 + tid] = res;
        else cc[tid] = res;
    } else if (r < 463) {
        const int r2 = r - 263;
        const int zz = r2 % 100, side = r2 / 100;
        float res = dot256(emb + (size_t)zz * 256, side ? W_aj : W_ai, tid)
                  + (side ? b_aj[tid] : b_ai[tid]);
        (side ? Aj : Ai)[(size_t)zz * 256 + tid] = res;
    } else if (r < 2026) {
        __shared__ int h[NZ];
        for (int i = tid; i < NZ; i += 256) h[i] = 0;
        __syncthreads();
        const int e = (r - 463) * 256 + tid;
        if (e < NEDGES) {
            atomicAdd(&cnt[esrc[e]], 1);
            atomicAdd(&h[z[edst[e]]], 1);
        }
        __syncthreads();
        for (int i = tid; i < NZ; i += 256) if (h[i]) atomicAdd(&zbins[i], h[i]);
    } else {
        const int i = (r - 2026) * 256 + tid;
        if (i < NATOMS) {
            out[OUT_Z + i] = (float)z[i];
            out[OUT_BATCH + i] = (float)batch[i];
        }
        if (i < 3 * NATOMS) out[OUT_POS + i] = pos[i];
    }
}

// ---------------- fused precompute B: M0/c0 + Gi/Gj ----------------

__global__ void kB(const float* __restrict__ W_dist, const float* __restrict__ b_dist,
                   const float* __restrict__ M1, float* __restrict__ M0, float* __restrict__ c0,
                   const float* __restrict__ Ai, const float* __restrict__ Aj,
                   const float* __restrict__ Wg1, const float* __restrict__ Wg2,
                   float* __restrict__ Gi, float* __restrict__ Gj)
{
    const int r = blockIdx.x, c = threadIdx.x;
    if (r < 51) {
        const float* a = (r < 50) ? (W_dist + (size_t)r * 256) : b_dist;
        float res = dot256(a, M1, c);
        if (r < 50) M0[(size_t)r * 256 + c] = res; else c0[c] = res;
    } else {
        const int r2 = r - 51;
        const int zz = r2 % 100, side = r2 / 100;
        float res = side ? dot256(Aj + (size_t)zz * 256, Wg2, c)
                         : dot256(Ai + (size_t)zz * 256, Wg1, c);
        (side ? Gj : Gi)[(size_t)zz * 256 + c] = res;
    }
}

// ---------------- fused precompute C: H tables + PTc ----------------

__global__ void kC(const float* __restrict__ Gi, const float* __restrict__ Gj,
                   const float* __restrict__ Wexp,
                   float* __restrict__ Hi, bf16* __restrict__ Hjb,
                   const float* __restrict__ M0, const float* __restrict__ M2,
                   const float* __restrict__ c0, const float* __restrict__ cc,
                   const float* __restrict__ b_exp, bf16* __restrict__ PTc)
{
    const int r = blockIdx.x;
    const int f = threadIdx.x;            // 128
    if (r < 1000) {
        const int zz = r / 10, g = r - zz * 10;
        const float* w  = Wexp + (size_t)g * 32768 + f;
        const float* gi = Gi + (size_t)zz * 256;
        const float* gj = Gj + (size_t)zz * 256;
        float a0=0,a1=0,a2=0,a3=0,b0=0,b1=0,b2=0,b3=0;
        for (int k = 0; k < 256; k += 4) {
            const float w0 = w[k*128], w1 = w[(k+1)*128], w2 = w[(k+2)*128], w3 = w[(k+3)*128];
            a0 += gi[k]*w0;   a1 += gi[k+1]*w1; a2 += gi[k+2]*w2; a3 += gi[k+3]*w3;
            b0 += gj[k]*w0;   b1 += gj[k+1]*w1; b2 += gj[k+2]*w2; b3 += gj[k+3]*w3;
        }
        Hi[(size_t)r * 128 + f] = (a0+a1)+(a2+a3);
        Hjb[(size_t)zz * 2048 + (g >> 3) * 1024 + f * 8 + (g & 7)] = (bf16)((b0+b1)+(b2+b3));
    } else {
        const int b = r - 1000;           // 0..591
        const int ck = b >> 4, kl = b & 15;
        const int k = ck * 16 + kl;
        float val = 0.f;
        if (k < 580) {
            const float* arow; int g; float bias = 0.f;
            if (k < 500)      { g = k / 50; arow = M0 + (size_t)(k - g * 50) * 256; }
            else if (k < 560) { const int jj = k - 500; g = jj / 6; arow = M2 + (size_t)(jj - g * 6) * 256; }
            else if (k < 570) { g = k - 560; arow = c0; }
            else              { g = k - 570; arow = cc; bias = b_exp[g * 128 + f]; }
            const float* w = Wexp + (size_t)g * 32768 + f;
            float s0=0,s1=0,s2=0,s3=0;
            for (int c2 = 0; c2 < 256; c2 += 4) {
                s0 += arow[c2]   * w[(c2)   * 128];
                s1 += arow[c2+1] * w[(c2+1) * 128];
                s2 += arow[c2+2] * w[(c2+2) * 128];
                s3 += arow[c2+3] * w[(c2+3) * 128];
            }
            val = (s0+s1)+(s2+s3) + bias;
        }
        PTc[(size_t)ck * 2048 + (kl >> 3) * 1024 + f * 8 + (kl & 7)] = (bf16)val;
    }
}

// ---------------- fused scans (block0: src CSR scan, block1: z scan) --------

__global__ void kD(const int* __restrict__ cnt, int* __restrict__ startp,
                   int* __restrict__ cursor,
                   const int* __restrict__ zbins, int* __restrict__ zcursor,
                   int* __restrict__ blk2z)
{
    const int tid = threadIdx.x;
    if (blockIdx.x == 0) {
        __shared__ int part[1024];
        const int chunk = (NATOMS + 1023) >> 10;
        const int lo = tid * chunk;
        const int hi = min(lo + chunk, NATOMS);
        int s = 0;
        for (int i = lo; i < hi; ++i) s += cnt[i];
        part[tid] = s;
        __syncthreads();
        for (int off = 1; off < 1024; off <<= 1) {
            int t = part[tid];
            if (tid >= off) t += part[tid - off];
            __syncthreads();
            part[tid] = t;
            __syncthreads();
        }
        int run = (tid == 0) ? 0 : part[tid - 1];
        for (int i = lo; i < hi; ++i) { startp[i] = run; cursor[i] = run; run += cnt[i]; }
    } else {
        __shared__ int st[NZ + 1];
        if (tid == 0) {
            int s = 0;
            for (int zz = 0; zz < NZ; ++zz) {
                st[zz] = s; zcursor[zz] = s;
                s += ((zbins[zz] + BE - 1) / BE) * BE;    // 128-aligned buckets
            }
            st[NZ] = s;
        }
        __syncthreads();
        for (int b = tid; b < NBLK; b += 1024) blk2z[b] = 0;
        __syncthreads();
        if (tid < NZ) {
            const int zz = tid;
            for (int b = st[zz] / BE; b < st[zz + 1] / BE; ++b) blk2z[b] = zz;
        }
    }
}

// ---------------- privatized bucket fill (z-sort scatter + src CSR fill) ----
#define ZF_EPB 1024
__global__ void __launch_bounds__(256) k_zfill(
    const int* __restrict__ edst, const int* __restrict__ z,
    const int* __restrict__ esrc,
    int* __restrict__ zcursor, int* __restrict__ cursor,
    int* __restrict__ perm, int* __restrict__ csr)
{
    __shared__ int h[NZ];
    __shared__ int base[NZ];
    const int t = threadIdx.x;
    for (int i = t; i < NZ; i += 256) h[i] = 0;
    __syncthreads();
    const int e0 = blockIdx.x * ZF_EPB;
    int rank[4], zb[4];
#pragma unroll
    for (int k2 = 0; k2 < 4; ++k2) {
        const int e = e0 + t + k2 * 256;
        if (e < NEDGES) { zb[k2] = z[edst[e]]; rank[k2] = atomicAdd(&h[zb[k2]], 1); }
        else zb[k2] = -1;
    }
    __syncthreads();
    for (int i = t; i < NZ; i += 256) base[i] = h[i] ? atomicAdd(&zcursor[i], h[i]) : 0;
    __syncthreads();
#pragma unroll
    for (int k2 = 0; k2 < 4; ++k2) {
        if (zb[k2] >= 0) {
            const int e = e0 + t + k2 * 256;
            const int pos = base[zb[k2]] + rank[k2];
            perm[pos] = e;
            const int p2 = atomicAdd(&cursor[esrc[e]], 1);
            csr[p2] = pos;
        }
    }
}

// ---------------- MFMA edge kernel: barrier-free hybrid LDS/L2 B ------------

__device__ __forceinline__ float coeff(int k, const unsigned* Gp, const float* gate,
                                       const float* sv, float C)
{
    if (k < 500) {
        const int g = k / 50, rb = k - g * 50;
        const unsigned w = Gp[rb >> 1];
        const unsigned bits = (rb & 1) ? (w & 0xffff0000u) : (w << 16);
        return gate[g] * __uint_as_float(bits);
    } else if (k < 560) {
        const int jj = k - 500;
        return gate[jj / 6] * sv[jj - (jj / 6) * 6];
    } else if (k < 570) {
        return C * gate[k - 560];
    } else if (k < 580) {
        return gate[k - 570];
    }
    return 0.0f;
}

__global__ void __launch_bounds__(256, 2) k_edge(
    const float* __restrict__ edge_vec,
    const int* __restrict__ perm, const int* __restrict__ blk2z,
    const float* __restrict__ tpar,
    const bf16* __restrict__ PTc, const bf16* __restrict__ Hjb,
    float* __restrict__ gates_ws, float* __restrict__ evb, bf16* __restrict__ eo)
{
    __shared__ __align__(16) bf16 Bs[(NLDSC + 1) * 2048];   // 61440 B

    const int t    = threadIdx.x;
    const int wid  = t >> 6;
    const int lane = t & 63;
    const int er   = lane & 31;
    const int kh   = lane >> 5;
    const bool khb = (kh != 0);
    const int base = blockIdx.x * BE;
    const int pid  = base + wid * 32 + er;

    if (perm[base] < 0) return;                 // all-dummy block (uniform)

    const int zb  = blk2z[blockIdx.x];
    const int eid = perm[pid];

    // ---- stage LDS chunks (loads first; latency hides under scalar math) ----
    const float4* PTc4 = (const float4*)PTc;
    float4 stg[NLDSC];
#pragma unroll
    for (int i = 0; i < NLDSC; ++i) stg[i] = PTc4[t + i * 256];
    const float4 hv = ((const float4*)(Hjb + (size_t)zb * 2048))[t];

    // ---- per-edge scalars ----
    float gate[NG], sv[6];
    float d = 1.0f, C = 0.0f, vx = 0.f, vy = 0.f, vz = 0.f;
    if (eid >= 0) {
        vx = edge_vec[eid * 3]; vy = edge_vec[eid * 3 + 1]; vz = edge_vec[eid * 3 + 2];
        d = sqrtf(vx * vx + vy * vy + vz * vz);
        C = (d < 5.0f) ? 0.5f * (__cosf(d * 0.6283185307179586f) + 1.0f) : 0.0f;
        float m = -3.0e38f;
#pragma unroll
        for (int g = 0; g < NG; ++g) {
            float r = 1.0f / fmaxf(fabsf(d - tpar[g]), 1e-8f);
            gate[g] = r; m = fmaxf(m, r);
        }
        float ss = 0.f;
#pragma unroll
        for (int g = 0; g < NG; ++g) { float ex = __expf(gate[g] - m); gate[g] = ex; ss += ex; }
        const float inv = 1.0f / ss;
#pragma unroll
        for (int g = 0; g < NG; ++g) gate[g] *= inv;
        const float d2 = d * d;
        sv[0] = d2; sv[1] = d2 * d; sv[2] = d2 * d2;
        sv[3] = sqrtf(d); sv[4] = __logf(d); sv[5] = d;
    } else {
#pragma unroll
        for (int g = 0; g < NG; ++g) gate[g] = 0.f;
#pragma unroll
        for (int m2 = 0; m2 < 6; ++m2) sv[m2] = 0.f;
    }

    // ---- packed Gaussian table (bf16 pairs, C folded in): 25 VGPRs ----
    unsigned Gp[25];
#pragma unroll
    for (int p = 0; p < 25; ++p) {
        const float t0 = d - (float)(2 * p) * DELTA_F;
        const float t1 = t0 - DELTA_F;
        const float g0 = C * __expf(-48.02f * t0 * t0);
        const float g1 = C * __expf(-48.02f * t1 * t1);
        Gp[p] = pack2bf(g0, g1);
    }

    if (kh == 0 && eid >= 0) {
        float* gw = gates_ws + (size_t)pid * 12;
#pragma unroll
        for (int g = 0; g < NG; ++g) gw[g] = gate[g];
        const float invd = 1.0f / d;
        *(float4*)(evb + (size_t)pid * 4) =
            make_float4(vx * invd, vy * invd, vz * invd, 0.0f);
    }

    // ---- write staged LDS, single barrier ----
    {
        float4* dst = (float4*)Bs;
#pragma unroll
        for (int i = 0; i < NLDSC; ++i) dst[t + i * 256] = stg[i];
        dst[t + NLDSC * 256] = hv;
    }
    __syncthreads();

    f32x16 acc0 = {}, acc1 = {}, acc2 = {}, acc3 = {};
    const int lanoff = kh * 1024 + er * 8;
    const bf16* Lp = Bs + lanoff;
    const bf16* Gb = PTc + lanoff;

#define MFMA4(AV, B0, B1, B2, B3) do { \
        acc0 = __builtin_amdgcn_mfma_f32_32x32x16_bf16(AV, B0, acc0, 0, 0, 0); \
        acc1 = __builtin_amdgcn_mfma_f32_32x32x16_bf16(AV, B1, acc1, 0, 0, 0); \
        acc2 = __builtin_amdgcn_mfma_f32_32x32x16_bf16(AV, B2, acc2, 0, 0, 0); \
        acc3 = __builtin_amdgcn_mfma_f32_32x32x16_bf16(AV, B3, acc3, 0, 0, 0); \
    } while (0)
#define LDB(P, V0, V1, V2, V3) \
        const bf16x8 V0 = *(const bf16x8*)(P); \
        const bf16x8 V1 = *(const bf16x8*)((P) + 256); \
        const bf16x8 V2 = *(const bf16x8*)((P) + 512); \
        const bf16x8 V3 = *(const bf16x8*)((P) + 768);

    // ---- Hj K-step (gate coefficients) ----
    {
        bf16x8 av;
#pragma unroll
        for (int j = 0; j < 8; ++j) {
            const float va = gate[j];
            const float vb = (j < 2) ? gate[8 + j] : 0.0f;
            av[j] = (bf16)(khb ? vb : va);
        }
        LDB(Lp + NLDSC * 2048, b0, b1, b2, b3);
        MFMA4(av, b0, b1, b2, b3);
    }

    // ---- prefetch first two global chunks ----
    bf16x8 c0, c1, c2, c3, n0, n1, n2, n3;
    {
        const bf16* bp = Gb + NLDSC * 2048;
        c0 = *(const bf16x8*)(bp);       c1 = *(const bf16x8*)(bp + 256);
        c2 = *(const bf16x8*)(bp + 512); c3 = *(const bf16x8*)(bp + 768);
    }
    {
        const bf16* bp = Gb + (NLDSC + 1) * 2048;
        n0 = *(const bf16x8*)(bp);       n1 = *(const bf16x8*)(bp + 256);
        n2 = *(const bf16x8*)(bp + 512); n3 = *(const bf16x8*)(bp + 768);
    }

    // ---- LDS chunks, no barriers ----
#pragma unroll
    for (int ks = 0; ks < NLDSC; ++ks) {
        bf16x8 av;
#pragma unroll
        for (int j = 0; j < 8; ++j) {
            const float va = coeff(ks * 16 + j,     Gp, gate, sv, C);
            const float vb = coeff(ks * 16 + 8 + j, Gp, gate, sv, C);
            av[j] = (bf16)(khb ? vb : va);
        }
        LDB(Lp + ks * 2048, b0, b1, b2, b3);
        MFMA4(av, b0, b1, b2, b3);
    }

    // ---- global chunks, depth-2 register prefetch ----
#pragma unroll
    for (int ks = NLDSC; ks < 37; ++ks) {
        const bf16x8 m0 = c0, m1 = c1, m2 = c2, m3 = c3;
        c0 = n0; c1 = n1; c2 = n2; c3 = n3;
        if (ks + 2 <= 36) {
            const bf16* bp = Gb + (size_t)(ks + 2) * 2048;
            n0 = *(const bf16x8*)(bp);       n1 = *(const bf16x8*)(bp + 256);
            n2 = *(const bf16x8*)(bp + 512); n3 = *(const bf16x8*)(bp + 768);
        }
        bf16x8 av;
#pragma unroll
        for (int j = 0; j < 8; ++j) {
            const float va = coeff(ks * 16 + j,     Gp, gate, sv, C);
            const float vb = coeff(ks * 16 + 8 + j, Gp, gate, sv, C);
            av[j] = (bf16)(khb ? vb : va);
        }
        MFMA4(av, m0, m1, m2, m3);
    }
#undef MFMA4
#undef LDB

    // ---- epilogue: block-local rows, bf16 stores ----
    bf16* eor = eo + (size_t)(base + wid * 32) * 128 + er;
#pragma unroll
    for (int r = 0; r < 16; ++r) {
        const int crow = (r & 3) + 8 * (r >> 2) + 4 * kh;
        bf16* p = eor + (size_t)crow * 128;
        p[0]  = (bf16)acc0[r];
        p[32] = (bf16)acc1[r];
        p[64] = (bf16)acc2[r];
        p[96] = (bf16)acc3[r];
    }
}

// ---------------- gather (+ exact Hi fold), unroll-4 ----------

__global__ void __launch_bounds__(256) k_gather(
    const bf16* __restrict__ eo, const float* __restrict__ evb,
    const float* __restrict__ gates_ws,
    const int* __restrict__ startp, const int* __restrict__ cnt,
    const int* __restrict__ csr, const int* __restrict__ zarr,
    const float* __restrict__ Hi, float* __restrict__ out)
{
    const int atom = blockIdx.x * 4 + (threadIdx.x >> 6);
    const int lane = threadIdx.x & 63;
    if (atom >= NATOMS) return;
    const int s = startp[atom], len = cnt[atom];
    const unsigned* eo32 = (const unsigned*)eo;
    const float4* ev4 = (const float4*)evb;
    const float4* gq  = (const float4*)gates_ws;
    float a0 = 0, a1 = 0, v00 = 0, v01 = 0, v10 = 0, v11 = 0, v20 = 0, v21 = 0;
    float gs[NG] = {}, e0g[NG] = {}, e1g[NG] = {}, e2g[NG] = {};

#define ACCE(EV, QA, QB, QC, U) do { \
        const float ga_[NG] = {QA.x, QA.y, QA.z, QA.w, QB.x, QB.y, QB.z, QB.w, QC.x, QC.y}; \
        _Pragma("unroll") \
        for (int g = 0; g < NG; ++g) { \
            gs[g] += ga_[g]; e0g[g] += EV.x * ga_[g]; \
            e1g[g] += EV.y * ga_[g]; e2g[g] += EV.z * ga_[g]; \
        } \
        const float y0 = __uint_as_float(U << 16); \
        const float y1 = __uint_as_float(U & 0xffff0000u); \
        a0 += y0; a1 += y1; \
        v00 += EV.x * y0; v01 += EV.x * y1; \
        v10 += EV.y * y0; v11 += EV.y * y1; \
        v20 += EV.z * y0; v21 += EV.z * y1; \
    } while (0)

    int i = 0;
    for (; i + 4 <= len; i += 4) {
        const int p0 = csr[s + i],     p1 = csr[s + i + 1];
        const int p2 = csr[s + i + 2], p3 = csr[s + i + 3];
        const float4 e0 = ev4[p0], e1 = ev4[p1], e2 = ev4[p2], e3 = ev4[p3];
        const unsigned u0 = eo32[(size_t)p0 * 64 + lane];
        const unsigned u1 = eo32[(size_t)p1 * 64 + lane];
        const unsigned u2 = eo32[(size_t)p2 * 64 + lane];
        const unsigned u3 = eo32[(size_t)p3 * 64 + lane];
        const float4 qa0 = gq[(size_t)p0 * 3], qb0 = gq[(size_t)p0 * 3 + 1], qc0 = gq[(size_t)p0 * 3 + 2];
        const float4 qa1 = gq[(size_t)p1 * 3], qb1 = gq[(size_t)p1 * 3 + 1], qc1 = gq[(size_t)p1 * 3 + 2];
        const float4 qa2 = gq[(size_t)p2 * 3], qb2 = gq[(size_t)p2 * 3 + 1], qc2 = gq[(size_t)p2 * 3 + 2];
        const float4 qa3 = gq[(size_t)p3 * 3], qb3 = gq[(size_t)p3 * 3 + 1], qc3 = gq[(size_t)p3 * 3 + 2];
        ACCE(e0, qa0, qb0, qc0, u0);
        ACCE(e1, qa1, qb1, qc1, u1);
        ACCE(e2, qa2, qb2, qc2, u2);
        ACCE(e3, qa3, qb3, qc3, u3);
    }
    for (; i < len; ++i) {
        const int p0 = csr[s + i];
        const float4 e0 = ev4[p0];
        const unsigned u0 = eo32[(size_t)p0 * 64 + lane];
        const float4 qa0 = gq[(size_t)p0 * 3], qb0 = gq[(size_t)p0 * 3 + 1], qc0 = gq[(size_t)p0 * 3 + 2];
        ACCE(e0, qa0, qb0, qc0, u0);
    }
#undef ACCE

    const float* Hrow = Hi + (size_t)zarr[atom] * 1280;
#pragma unroll
    for (int g = 0; g < NG; ++g) {
        const float2 h2 = *(const float2*)(Hrow + g * 128 + 2 * lane);
        a0  += gs[g] * h2.x;  a1  += gs[g] * h2.y;
        v00 += e0g[g] * h2.x; v01 += e0g[g] * h2.y;
        v10 += e1g[g] * h2.x; v11 += e1g[g] * h2.y;
        v20 += e2g[g] * h2.x; v21 += e2g[g] * h2.y;
    }
    float* ao = out + (size_t)atom * 128;
    *(float2*)(ao + 2 * lane) = make_float2(a0, a1);
    float* vp = out + OUT_VEC + (size_t)atom * 384;
    *(float2*)(vp + 2 * lane)       = make_float2(v00, v01);
    *(float2*)(vp + 128 + 2 * lane) = make_float2(v10, v11);
    *(float2*)(vp + 256 + 2 * lane) = make_float2(v20, v21);
}

// ---------------- launch ----------------

extern "C" void kernel_launch(void* const* d_in, const int* in_sizes, int n_in,
                              void* d_out, int out_size, void* d_ws, size_t ws_size,
                              hipStream_t stream)
{
    const int*   z        = (const int*)d_in[0];
    const float* pos      = (const float*)d_in[1];
    const int*   batch    = (const int*)d_in[2];
    const int*   esrc     = (const int*)d_in[3];
    const int*   edst     = esrc + NEDGES;
    const float* edge_vec = (const float*)d_in[4];
    const float* emb      = (const float*)d_in[5];
    const float* W_dist   = (const float*)d_in[6];
    const float* b_dist   = (const float*)d_in[7];
    const float* W_dt     = (const float*)d_in[8];
    const float* b_dt     = (const float*)d_in[9];
    const float* W_ai     = (const float*)d_in[10];
    const float* b_ai     = (const float*)d_in[11];
    const float* W_aj     = (const float*)d_in[12];
    const float* b_aj     = (const float*)d_in[13];
    const float* W_gamma  = (const float*)d_in[14];
    const float* b_gamma  = (const float*)d_in[15];
    const float* W_exp    = (const float*)d_in[16];
    const float* b_exp    = (const float*)d_in[17];
    const float* tpar     = (const float*)d_in[18];

    float* out = (float*)d_out;
    float* W   = (float*)d_ws;

    const float* Wg1 = W_gamma;
    const float* Wg2 = W_gamma + 256 * 256;
    const float* Wg3 = W_gamma + 512 * 256;

    float* M1 = W + WS_M1;
    float* M0 = W + WS_M0;
    float* c0 = W + WS_C0;
    float* M2 = W + WS_M2;
    float* cc = W + WS_CC;
    float* Ai = W + WS_AI;
    float* Aj = W + WS_AJ;
    float* Gi = W + WS_GI;
    float* Gj = W + WS_GJ;
    float* Hi = W + WS_HI;
    bf16*  Hjb = (bf16*)(W + WS_HJB);
    bf16*  PTc = (bf16*)(W + WS_PTC);
    float* gates = W + WS_GT;
    float* evb   = W + WS_EV;
    bf16*  eo    = (bf16*)(W + WS_EO);
    int*   I     = (int*)(W + WS_I);
    int* cnt    = I + I_CNT;
    int* startp = I + I_START;
    int* cursor = I + I_CUR;
    int* csr    = I + I_CSR;
    int* zbins  = I + I_ZB;
    int* zcur   = I + I_ZC;
    int* b2z    = I + I_B2Z;
    int* perm   = I + I_PERM;

    hipMemsetAsync(cnt, 0, NATOMS * sizeof(int), stream);
    hipMemsetAsync(zbins, 0, 128 * sizeof(int), stream);
    hipMemsetAsync(perm, 0xFF, (size_t)NBLK * BE * sizeof(int), stream);
    hipMemsetAsync(Hjb, 0, 100 * 2048 * sizeof(bf16), stream);

    kA<<<2613, 256, 0, stream>>>(W_dt, b_dt, b_gamma, Wg3, M1, M2, cc,
                                 emb, W_ai, b_ai, W_aj, b_aj, Ai, Aj,
                                 esrc, edst, z, cnt, zbins, pos, batch, out);
    kB<<<251, 256, 0, stream>>>(W_dist, b_dist, M1, M0, c0, Ai, Aj, Wg1, Wg2, Gi, Gj);
    kC<<<1592, 128, 0, stream>>>(Gi, Gj, W_exp, Hi, Hjb, M0, M2, c0, cc, b_exp, PTc);
    kD<<<2, 1024, 0, stream>>>(cnt, startp, cursor, zbins, zcur, b2z);
    k_zfill<<<(NEDGES + ZF_EPB - 1) / ZF_EPB, 256, 0, stream>>>(edst, z, esrc, zcur, cursor, perm, csr);

    k_edge<<<NBLK, 256, 0, stream>>>(edge_vec, perm, b2z, tpar, PTc, Hjb, gates, evb, eo);
    k_gather<<<(NATOMS + 3) / 4, 256, 0, stream>>>(eo, evb, gates, startp, cnt, csr, z, Hi, out);
}